// Round 12
// baseline (463.723 us; speedup 1.0000x reference)
//
#include <hip/hip_runtime.h>

#define S 2048
#define HID 2048
#define NH 16
#define DH 128
#define VOC 128
#define LCAP 128
#define K2EXP 0.12752551286084112f   // (1/sqrt(128)) * log2(e)
#define RTHR 62.0f                   // defer-max threshold in raw-score units
#define NEGS -3.0e38f

typedef __bf16 bf16_t;
typedef __attribute__((ext_vector_type(8))) __bf16 bf16x8;
typedef __attribute__((ext_vector_type(4))) __bf16 bf16x4;
typedef __attribute__((ext_vector_type(4))) float f32x4;
typedef __attribute__((ext_vector_type(16))) float f32x16;

typedef __attribute__((address_space(1))) unsigned int guint;
typedef __attribute__((address_space(3))) unsigned int luint;

#define MFMA16 __builtin_amdgcn_mfma_f32_16x16x32_bf16
#define MFMA32 __builtin_amdgcn_mfma_f32_32x32x16_bf16

__device__ __forceinline__ void gl_lds16(const void* g, void* l) {
  __builtin_amdgcn_global_load_lds((guint*)(unsigned long long)g,
                                   (luint*)(unsigned)(unsigned long long)l,
                                   16, 0, 0);
}

__device__ __forceinline__ unsigned cvtpk(float lo, float hi) {
  unsigned r;
  asm("v_cvt_pk_bf16_f32 %0, %1, %2" : "=v"(r) : "v"(lo), "v"(hi));
  return r;
}
__device__ __forceinline__ void plswap(unsigned& a, unsigned& b) {
  asm volatile("v_permlane32_swap_b32 %0, %1" : "+v"(a), "+v"(b));
}
__device__ __forceinline__ bf16x8 mk8(unsigned d0, unsigned d1, unsigned d2, unsigned d3) {
  union { unsigned u[4]; bf16x8 v; } x;
  x.u[0] = d0; x.u[1] = d1; x.u[2] = d2; x.u[3] = d3;
  return x.v;
}

// ---------------- mask precompute: intervals + starts + landmarks + 32q-stripe meta ----------------
__global__ __launch_bounds__(256) void maskprep2(const int* __restrict__ tokens,
                                                 const unsigned char* __restrict__ seg,
                                                 const unsigned char* __restrict__ spc,
                                                 int4* __restrict__ mi,
                                                 int* __restrict__ lq,
                                                 unsigned long long* __restrict__ lmask,
                                                 int2* __restrict__ smeta) {
  __shared__ int ssp[257], ssg[257], smw[257], sms[257], sfl[257];
  __shared__ int fpre[2048];
  __shared__ int ns64[64];
  __shared__ unsigned long long lmk[32];
  __shared__ int cdet[2];
  int t = threadIdx.x;
  if (t < 2) cdet[t] = 0;
  if (t < 32) lmk[t] = 0ull;
  __syncthreads();
  {
    int nz = ((t & 3) != 0 && seg[t]) ? 1 : 0;
    int fc = ((t & 3) == 3 && seg[t] == 0x3f) ? 1 : 0;
    if (nz) atomicAdd(&cdet[0], 1);
    if (fc) atomicAdd(&cdet[1], 1);
  }
  __syncthreads();
  int lay = (cdet[1] > 8) ? 2 : ((cdet[0] > 4) ? 1 : 0);
  auto getb = [&](const unsigned char* p, int i) -> int {
    if (lay == 1) return p[i] != 0;
    if (lay == 2) return ((const float*)p)[i] != 0.f;
    return ((const int*)p)[i] != 0;
  };
  int base = t * 8;
  int spv[8], sgv[8], npv[8], fv[8];
  int a = 0, b = 0, mw = 0, ms = 0, fs = 0;
  for (int j = 0; j < 8; j++) {
    int i = base + j;
    spv[j] = getb(spc, i);
    sgv[j] = 1 - getb(seg, i);
    npv[j] = (tokens[i] != 127) ? 1 : 0;
    fv[j] = spv[j] & sgv[j] & npv[j];
    a += spv[j]; b += sgv[j]; fs += fv[j];
    if (i >= 1 && spv[j]) mw = (i + 1 > mw) ? i + 1 : mw;
    if (i >= 1 && sgv[j]) ms = (i + 1 > ms) ? i + 1 : ms;
  }
  ssp[t + 1] = a; ssg[t + 1] = b; smw[t + 1] = mw; sms[t + 1] = ms; sfl[t + 1] = fs;
  if (t == 0) { ssp[0] = 0; ssg[0] = 0; smw[0] = 0; sms[0] = 0; sfl[0] = 0; }
  __syncthreads();
  for (int off = 1; off < 256; off <<= 1) {
    int v0 = 0, v1 = 0, v2 = 0, v3 = 0, v4 = 0;
    if (t + 1 > off) { v0 = ssp[t+1-off]; v1 = ssg[t+1-off]; v2 = smw[t+1-off]; v3 = sms[t+1-off]; v4 = sfl[t+1-off]; }
    __syncthreads();
    ssp[t + 1] += v0; ssg[t + 1] += v1;
    if (v2 > smw[t + 1]) smw[t + 1] = v2;
    if (v3 > sms[t + 1]) sms[t + 1] = v3;
    sfl[t + 1] += v4;
    __syncthreads();
  }
  if ((t & 3) == 0) {
    int ws = smw[t], ss = sms[t];
    ns64[t >> 2] = ws < ss ? ws : ss;
  }
  int esp = ssp[t], esg = ssg[t], ef = sfl[t];
  for (int j = 0; j < 8; j++) {
    int i = base + j;
    int wint = (i == 0) ? (1 + spv[j]) : (1 + esp);
    int sint = (i == 0) ? (1 + sgv[j]) : (1 + esg);
    mi[i] = make_int4(npv[j] | (spv[j] << 1) | (sgv[j] << 2), wint, sint, 0);
    fpre[i] = ef;
    int lqv = (fv[j] && ef < LCAP) ? ef : -1;
    lq[i] = lqv;
    if (lqv >= 0) atomicOr(&lmk[i >> 6], 1ull << (i & 63));
    esp += spv[j]; esg += sgv[j]; ef += fv[j];
  }
  __syncthreads();
  if (t < 32) lmask[t] = lmk[t];
  if (t < 64) {
    int nsTile = ns64[t] >> 5;           // 32-kv tile index
    int lc = fpre[nsTile * 32];          // landmarks strictly below near zone
    if (lc > LCAP) lc = LCAP;
    smeta[t] = make_int2(nsTile, lc);
  }
}

// ---------------- full mask bit table: cmask[word][q], word=kv/32 ----------------
__global__ __launch_bounds__(256) void bitgen(const int4* __restrict__ mi,
                                              unsigned* __restrict__ cmask) {
  __shared__ int4 km[32];
  int w = blockIdx.x;
  int t = threadIdx.x;
  int q = blockIdx.y * 256 + t;
  if (t < 32) km[t] = mi[w * 32 + t];
  __syncthreads();
  int4 mq = mi[q];
  unsigned word = 0;
  #pragma unroll
  for (int j = 0; j < 32; j++) {
    int kv = w * 32 + j;
    int4 mk = km[j];
    bool v = ((mq.x & mk.x) & 1) &&
             ((mk.x & 2) || (mq.y == mk.y)) &&
             ((mk.x & 4) || (mq.z == mk.z)) &&
             (kv <= q);
    word |= (v ? 1u : 0u) << j;
  }
  cmask[(size_t)w * S + q] = word;
}

// ---------------- fused persistent net: embed + 4 attention layers, dataflow flags ----------------
// Buffers: stage s output hidden = hbBase + s*HBN  (s=0..4; stage4 = final, hb only)
//          stage s vtb tiles     = vtbBase + s*HBN (s=0..3)
//          stage s landmarks     = lBase + s*2*LBN (hbL then vtbL)
// flag[s][h][st] (s=0..3) set when stripe st of head h has written stage-s output.
__global__ __launch_bounds__(64, 2) void fused_net(const int* __restrict__ tokens,
                                                   const float* __restrict__ emb,
                                                   const unsigned* __restrict__ cmask,
                                                   const int4* __restrict__ mi,
                                                   const int2* __restrict__ smeta,
                                                   const int* __restrict__ lq,
                                                   const unsigned long long* __restrict__ lmask,
                                                   bf16_t* __restrict__ hbBase,
                                                   bf16_t* __restrict__ vtbBase,
                                                   bf16_t* __restrict__ lBase,
                                                   unsigned* __restrict__ flg) {
  __shared__ __align__(16) char lds_raw[32768];   // 2 bufs x (K 8KB + Vt 8KB); buf0 aliases tl

  const size_t HBN = (size_t)S * HID;             // 4M elems
  const size_t LBN = (size_t)LCAP * HID;          // 256K elems

  int h = blockIdx.x, st = blockIdx.y;            // st 0..63, 32 q each
  int2 sm = smeta[st];
  int nsT = sm.x, lcount = sm.y;
  int nNear = st + 1 - nsT;
  int nLT = (lcount + 31) >> 5;
  int nIter = nNear + nLT;

  int l = threadIdx.x, l31 = l & 31, hi = l >> 5;
  int q0 = 32 * st, q = q0 + l31;
  int npq = mi[q].x & 1;
  int swz = l31 & 7;

  bf16_t* tl = (bf16_t*)lds_raw;                  // 32 x 132 bf16 tile
  bf16x8 qf[8];

  auto emit = [&](int s, bool wT) {
    bf16_t* ohb = hbBase + (size_t)s * HBN;
    int c4 = l & 3;
    #pragma unroll
    for (int g = 0; g < 2; g++) {
      int row = g * 16 + (l >> 2);
      #pragma unroll
      for (int k = 0; k < 4; k++) {
        bf16x8 v = *(const bf16x8*)(tl + row * 132 + c4 * 32 + k * 8);
        *(bf16x8*)(ohb + (size_t)(q0 + row) * HID + h * DH + c4 * 32 + k * 8) = v;
      }
    }
    if (wT) {
      bf16_t* vt = vtbBase + (size_t)s * HBN + ((size_t)(h * 64) + st) * 4096;
      #pragma unroll
      for (int s2 = 0; s2 < 8; s2++) {
        int d = s2 * 16 + (l >> 2);
        bf16x8 v;
        #pragma unroll
        for (int e = 0; e < 8; e++)
          v[e] = tl[(8 * ((l & 3) ^ (d & 3)) + e) * 132 + d];
        *(bf16x8*)(vt + s2 * 512 + l * 8) = v;
      }
      bf16_t* ohbL = lBase + (size_t)s * (2 * LBN);
      bf16_t* ovtL = ohbL + LBN;
      unsigned lm32 = (unsigned)(lmask[st >> 1] >> ((st & 1) * 32));
      while (lm32) {
        int r = __builtin_ctz(lm32);
        lm32 &= lm32 - 1;
        int li = lq[q0 + r];
        if (li >= 0) {
          #pragma unroll
          for (int half = 0; half < 2; half++) {
            int dd = l + 64 * half;
            bf16_t vv = tl[r * 132 + dd];
            ohbL[(size_t)li * HID + h * DH + dd] = vv;
            ovtL[((size_t)(h * 4) + (li >> 5)) * 4096 + dd * 32 + (((li & 31) >> 3) ^ (dd & 3)) * 8 + (li & 7)] = vv;
          }
        }
      }
    }
  };

  auto load_qf = [&]() {
    #pragma unroll
    for (int ks = 0; ks < 8; ks++)
      qf[ks] = *(const bf16x8*)(tl + l31 * 132 + ks * 16 + hi * 8);
    asm volatile("s_waitcnt lgkmcnt(0)" ::: "memory");
  };

  auto set_flag = [&](int s) {
    __threadfence();
    if (l == 0)
      __hip_atomic_store(flg + ((size_t)s * NH + h) * 64 + st, 1u,
                         __ATOMIC_RELEASE, __HIP_MEMORY_SCOPE_AGENT);
  };

  auto wait_stage = [&](int s) {
    const unsigned* f = flg + ((size_t)s * NH + h) * 64;
    int idx = (l <= st) ? l : st;
    for (;;) {
      unsigned v = __hip_atomic_load(f + idx, __ATOMIC_RELAXED, __HIP_MEMORY_SCOPE_AGENT);
      if (__all(v != 0)) break;
      __builtin_amdgcn_s_sleep(1);
    }
    __threadfence();
  };

  // ---- stage 0: embed my 32 tokens, head-h slice ----
  {
    int row = l >> 1, hf = l & 1;
    int tok = tokens[q0 + row];
    const float4* src = (const float4*)(emb + (size_t)tok * HID + h * DH + hf * 64);
    #pragma unroll
    for (int k = 0; k < 8; k++) {
      float4 f0 = src[2 * k], f1 = src[2 * k + 1];
      #pragma unroll
      for (int e = 0; e < 4; e++) {
        float fe = e == 0 ? f0.x : e == 1 ? f0.y : e == 2 ? f0.z : f0.w;
        tl[row * 132 + hf * 64 + k * 8 + e] = (bf16_t)fe;
      }
      #pragma unroll
      for (int e = 0; e < 4; e++) {
        float fe = e == 0 ? f1.x : e == 1 ? f1.y : e == 2 ? f1.z : f1.w;
        tl[row * 132 + hf * 64 + k * 8 + 4 + e] = (bf16_t)fe;
      }
    }
  }
  emit(0, true);
  load_qf();
  set_flag(0);

  // ---- 4 attention layers ----
  for (int L = 0; L < 4; L++) {
    wait_stage(L);
    const bf16_t* ihb  = hbBase + (size_t)L * HBN;
    const bf16_t* ivtb = vtbBase + (size_t)L * HBN;
    const bf16_t* ihbL = lBase + (size_t)L * (2 * LBN);
    const bf16_t* ivtL = ihbL + LBN;

    auto STAGE = [&](int i, int b) {
      const bf16_t* Kbase; const bf16_t* Vtile;
      if (i < nNear) {
        int t = nsT + i;
        Kbase = ihb + (size_t)(t * 32) * HID + h * DH;
        Vtile = ivtb + ((size_t)(h * 64) + t) * 4096;
      } else {
        int j = i - nNear;
        Kbase = ihbL + (size_t)(j * 32) * HID + h * DH;
        Vtile = ivtL + ((size_t)(h * 4) + j) * 4096;
      }
      bf16_t* Kb = (bf16_t*)(lds_raw + b * 16384);
      bf16_t* Vb = (bf16_t*)(lds_raw + b * 16384 + 8192);
      #pragma unroll
      for (int i2 = 0; i2 < 8; i2++) {
        int rowK = i2 * 4 + (l >> 4); int chK = (l & 15) ^ (rowK & 7);
        gl_lds16(Kbase + (size_t)rowK * HID + chK * 8, Kb + i2 * 512);
      }
      #pragma unroll
      for (int i2 = 0; i2 < 8; i2++)
        gl_lds16(Vtile + i2 * 512 + l * 8, Vb + i2 * 512);
    };

    auto getmask = [&](int i) -> unsigned {
      if (i < nNear) return cmask[(size_t)(nsT + i) * S + q];
      int rem = lcount - (i - nNear) * 32;
      unsigned w0 = (rem >= 32) ? 0xffffffffu : ((rem <= 0) ? 0u : ((1u << rem) - 1u));
      return npq ? w0 : 0u;
    };

    f32x16 acc[4];
    #pragma unroll
    for (int i = 0; i < 4; i++)
      #pragma unroll
      for (int r = 0; r < 16; r++) acc[i][r] = 0.f;
    float m = -1e30f, lsum = 0.f;

    STAGE(0, 0);
    for (int i = 0; i < nIter; i++) {
      int b = i & 1;
      if (i + 1 < nIter) {
        STAGE(i + 1, b ^ 1);
        asm volatile("s_waitcnt vmcnt(16)" ::: "memory");
      } else {
        asm volatile("s_waitcnt vmcnt(0)" ::: "memory");
      }
      unsigned w0 = getmask(i);

      if (__any(w0 != 0u)) {
        const bf16_t* Kb = (const bf16_t*)(lds_raw + b * 16384);
        const bf16_t* Vb = (const bf16_t*)(lds_raw + b * 16384 + 8192);
        f32x16 s;
        #pragma unroll
        for (int r = 0; r < 16; r++) s[r] = 0.f;
        const bf16_t* kp = Kb + l31 * 128;
        #pragma unroll
        for (int ks = 0; ks < 8; ks++) {
          bf16x8 kf = *(const bf16x8*)(kp + (((2 * ks + hi) ^ swz) * 8));
          s = MFMA32(kf, qf[ks], s, 0, 0, 0);
        }

        float sv[16];
        float mx = NEGS;
        #pragma unroll
        for (int r = 0; r < 16; r++) {
          int bit = (r & 3) + 8 * (r >> 2) + 4 * hi;
          sv[r] = ((w0 >> bit) & 1u) ? s[r] : NEGS;
          mx = fmaxf(mx, sv[r]);
        }
        mx = fmaxf(mx, __shfl_xor(mx, 32, 64));
        if (__any(mx > m + RTHR)) {
          float mn = fmaxf(m, mx);
          float al = exp2f((m - mn) * K2EXP);
          m = mn; lsum *= al;
          #pragma unroll
          for (int r = 0; r < 16; r++) {
            float alr = __shfl(al, (r & 3) + 8 * (r >> 2) + 4 * hi, 64);
            #pragma unroll
            for (int d = 0; d < 4; d++) acc[d][r] *= alr;
          }
        }
        float mk = m * K2EXP;
        float p[16], ps = 0.f;
        #pragma unroll
        for (int r = 0; r < 16; r++) {
          p[r] = exp2f(__builtin_fmaf(sv[r], K2EXP, -mk));
          ps += p[r];
        }
        ps += __shfl_xor(ps, 32, 64);
        lsum += ps;

        bf16x8 pa[2];
        {
          unsigned a0 = cvtpk(p[0], p[1]),   a1 = cvtpk(p[2], p[3]);
          unsigned b0 = cvtpk(p[4], p[5]),   b1 = cvtpk(p[6], p[7]);
          unsigned a2 = cvtpk(p[8], p[9]),   a3 = cvtpk(p[10], p[11]);
          unsigned b2 = cvtpk(p[12], p[13]), b3 = cvtpk(p[14], p[15]);
          plswap(a0, b0); plswap(a1, b1); plswap(a2, b2); plswap(a3, b3);
          pa[0] = mk8(a0, a1, b0, b1);
          pa[1] = mk8(a2, a3, b2, b3);
        }

        #pragma unroll
        for (int db = 0; db < 4; db++) {
          const bf16_t* vr = Vb + (32 * db + l31) * 32;
          #pragma unroll
          for (int ks = 0; ks < 2; ks++) {
            bf16x8 vf = *(const bf16x8*)(vr + (((2 * ks + hi) ^ (l31 & 3)) * 8));
            acc[db] = MFMA32(pa[ks], vf, acc[db], 0, 0, 0);
          }
        }
      }
    }

    // epilogue: normalize into tl (buf0 — all staging reads complete)
    float inv = (lsum > 0.f) ? 1.f / lsum : 0.f;
    #pragma unroll
    for (int r = 0; r < 16; r++) {
      int qr = (r & 3) + 8 * (r >> 2) + 4 * hi;
      float ivr = __shfl(inv, qr, 64);
      #pragma unroll
      for (int db = 0; db < 4; db++)
        tl[qr * 132 + db * 32 + l31] = (bf16_t)(acc[db][r] * ivr);
    }
    emit(L + 1, L < 3);
    if (L < 3) {
      load_qf();
      set_flag(L + 1);
    }
  }
}

// ---------------- lm head weight convert ----------------
__global__ __launch_bounds__(256) void wcvt(const float* __restrict__ w, bf16_t* __restrict__ wb) {
  int i = blockIdx.x * 256 + threadIdx.x;
  float4 f = ((const float4*)w)[i];
  bf16x4 v;
  v[0] = (bf16_t)f.x; v[1] = (bf16_t)f.y; v[2] = (bf16_t)f.z; v[3] = (bf16_t)f.w;
  *(bf16x4*)(wb + (size_t)i * 4) = v;
}

// ---------------- lm head + segment head fused ----------------
__global__ __launch_bounds__(256) void lmseg_head(const bf16_t* __restrict__ hb,
                                                  const bf16_t* __restrict__ wbf,
                                                  const float* __restrict__ bias,
                                                  const float* __restrict__ sw,
                                                  const float* __restrict__ sb,
                                                  float* __restrict__ out,
                                                  float* __restrict__ outseg) {
  __shared__ float red[4][16][130];
  int tid = threadIdx.x;
  int w = tid >> 6, l = tid & 63, l16 = l & 15, g = l >> 4;
  int t0 = blockIdx.x * 16;
  f32x4 acc[8];
  #pragma unroll
  for (int i = 0; i < 8; i++) acc[i] = (f32x4){0.f, 0.f, 0.f, 0.f};
  const bf16_t* arow = hb + (size_t)(t0 + l16) * HID + w * 512;
  for (int k0 = 0; k0 < 512; k0 += 32) {
    bf16x8 af = *(const bf16x8*)(arow + k0 + g * 8);
    #pragma unroll
    for (int vt = 0; vt < 8; vt++) {
      bf16x8 bf_ = *(const bf16x8*)(wbf + (size_t)(vt * 16 + l16) * HID + w * 512 + k0 + g * 8);
      acc[vt] = MFMA16(af, bf_, acc[vt], 0, 0, 0);
    }
  }
  #pragma unroll
  for (int vt = 0; vt < 8; vt++)
    #pragma unroll
    for (int r = 0; r < 4; r++)
      red[w][4 * g + r][vt * 16 + l16] = acc[vt][r];
  __syncthreads();
  int q = tid >> 4, vc = (tid & 15) * 8;
  #pragma unroll
  for (int j = 0; j < 8; j++) {
    float s = red[0][q][vc + j] + red[1][q][vc + j] + red[2][q][vc + j] + red[3][q][vc + j];
    out[(size_t)(t0 + q) * VOC + vc + j] = s + bias[vc + j];
  }
  {
    int c = tid & 15;
    const bf16_t* hrow = hb + (size_t)(t0 + q) * HID + c * 128;
    float s0 = 0.f, s1 = 0.f;
    #pragma unroll
    for (int i = 0; i < 16; i++) {
      bf16x8 v = *(const bf16x8*)(hrow + i * 8);
      const float4* w0p = (const float4*)(sw + c * 128 + i * 8);
      const float4* w1p = (const float4*)(sw + HID + c * 128 + i * 8);
      float4 x0 = w0p[0], x1 = w0p[1], y0 = w1p[0], y1 = w1p[1];
      s0 += (float)v[0]*x0.x + (float)v[1]*x0.y + (float)v[2]*x0.z + (float)v[3]*x0.w
          + (float)v[4]*x1.x + (float)v[5]*x1.y + (float)v[6]*x1.z + (float)v[7]*x1.w;
      s1 += (float)v[0]*y0.x + (float)v[1]*y0.y + (float)v[2]*y0.z + (float)v[3]*y0.w
          + (float)v[4]*y1.x + (float)v[5]*y1.y + (float)v[6]*y1.z + (float)v[7]*y1.w;
    }
    #pragma unroll
    for (int off = 1; off < 16; off <<= 1) {
      s0 += __shfl_xor(s0, off, 64);
      s1 += __shfl_xor(s1, off, 64);
    }
    if (c == 0) {
      outseg[(size_t)(t0 + q) * 2] = s0 + sb[0];
      outseg[(size_t)(t0 + q) * 2 + 1] = s1 + sb[1];
    }
  }
}

extern "C" void kernel_launch(void* const* d_in, const int* in_sizes, int n_in,
                              void* d_out, int out_size, void* d_ws, size_t ws_size,
                              hipStream_t stream) {
  const int* tokens = (const int*)d_in[0];
  const unsigned char* seg = (const unsigned char*)d_in[1];
  const unsigned char* spc = (const unsigned char*)d_in[2];
  const float* emb_w = (const float*)d_in[3];
  const float* lm_w = (const float*)d_in[4];
  const float* lm_b = (const float*)d_in[5];
  const float* seg_w = (const float*)d_in[6];
  const float* seg_b = (const float*)d_in[7];

  char* ws = (char*)d_ws;
  int4* mi = (int4*)ws;                                              // 32KB  @0
  unsigned* cmask = (unsigned*)(ws + (1u << 20));                    // 512KB @1MB
  int* lq = (int*)(ws + (1u << 20) + (512u << 10));                  // 8KB
  unsigned long long* lmask = (unsigned long long*)(ws + (1u << 20) + (520u << 10)); // 256B
  int2* smeta = (int2*)(ws + (1u << 20) + (524u << 10));             // 512B
  bf16_t* wbf = (bf16_t*)(ws + (2u << 20));                          // 512KB @2MB
  unsigned* flg = (unsigned*)(ws + (3u << 20));                      // 16KB @3MB
  bf16_t* hbBase  = (bf16_t*)(ws + (16u << 20));                     // 5 x 8MB @16MB
  bf16_t* vtbBase = (bf16_t*)(ws + (56u << 20));                     // 4 x 8MB @56MB
  bf16_t* lBase   = (bf16_t*)(ws + (88u << 20));                     // 4 x 1MB @88MB
  float* out = (float*)d_out;

  hipMemsetAsync(flg, 0, 4 * NH * 64 * sizeof(unsigned), stream);
  maskprep2<<<1, 256, 0, stream>>>(tokens, seg, spc, mi, lq, lmask, smeta);
  bitgen<<<dim3(64, 8), 256, 0, stream>>>(mi, cmask);
  wcvt<<<(VOC * HID / 4) / 256, 256, 0, stream>>>(lm_w, wbf);
  fused_net<<<dim3(NH, 64), 64, 0, stream>>>(tokens, emb_w, cmask, mi, smeta, lq, lmask,
                                             hbBase, vtbBase, lBase, flg);
  bf16_t* hbF = hbBase + (size_t)4 * S * HID;
  lmseg_head<<<S / 16, 256, 0, stream>>>(hbF, wbf, lm_b, seg_w, seg_b, out, out + (size_t)S * VOC);
}

// Round 13
// 137.567 us; speedup vs baseline: 3.3709x; 3.3709x over previous
//
#include <hip/hip_runtime.h>

#define S 2048
#define HID 2048
#define NH 16
#define DH 128
#define VOC 128
#define LCAP 128
#define K2EXP 0.12752551286084112f   // (1/sqrt(128)) * log2(e)
#define RTHR 62.0f                   // defer-max threshold in raw-score units
#define NEGS -3.0e38f

typedef __bf16 bf16_t;
typedef __attribute__((ext_vector_type(8))) __bf16 bf16x8;
typedef __attribute__((ext_vector_type(4))) __bf16 bf16x4;
typedef __attribute__((ext_vector_type(4))) float f32x4;
typedef __attribute__((ext_vector_type(16))) float f32x16;

typedef __attribute__((address_space(1))) unsigned int guint;
typedef __attribute__((address_space(3))) unsigned int luint;

#define MFMA16 __builtin_amdgcn_mfma_f32_16x16x32_bf16
#define MFMA32 __builtin_amdgcn_mfma_f32_32x32x16_bf16

__device__ __forceinline__ void gl_lds16(const void* g, void* l) {
  __builtin_amdgcn_global_load_lds((guint*)(unsigned long long)g,
                                   (luint*)(unsigned)(unsigned long long)l,
                                   16, 0, 0);
}

__device__ __forceinline__ unsigned cvtpk(float lo, float hi) {
  unsigned r;
  asm("v_cvt_pk_bf16_f32 %0, %1, %2" : "=v"(r) : "v"(lo), "v"(hi));
  return r;
}
__device__ __forceinline__ void plswap(unsigned& a, unsigned& b) {
  asm volatile("v_permlane32_swap_b32 %0, %1" : "+v"(a), "+v"(b));
}
__device__ __forceinline__ bf16x8 mk8(unsigned d0, unsigned d1, unsigned d2, unsigned d3) {
  union { unsigned u[4]; bf16x8 v; } x;
  x.u[0] = d0; x.u[1] = d1; x.u[2] = d2; x.u[3] = d3;
  return x.v;
}

// vtb layout: per (head h, 32-kv tile t) a contiguous 4096-halfword block:
//   vtb[(h*64+t)*4096 + d*32 + c*8 + e] = h_hidden[kv = 32t + 8*(c^(d&3)) + e][h*DH + d]

// ---------------- mask precompute: intervals + starts + landmarks + 32q-stripe meta ----------------
__global__ __launch_bounds__(256) void maskprep2(const int* __restrict__ tokens,
                                                 const unsigned char* __restrict__ seg,
                                                 const unsigned char* __restrict__ spc,
                                                 int4* __restrict__ mi,
                                                 int* __restrict__ lq,
                                                 unsigned long long* __restrict__ lmask,
                                                 int2* __restrict__ smeta) {
  __shared__ int ssp[257], ssg[257], smw[257], sms[257], sfl[257];
  __shared__ int fpre[2048];
  __shared__ int ns64[64];
  __shared__ unsigned long long lmk[32];
  __shared__ int cdet[2];
  int t = threadIdx.x;
  if (t < 2) cdet[t] = 0;
  if (t < 32) lmk[t] = 0ull;
  __syncthreads();
  {
    int nz = ((t & 3) != 0 && seg[t]) ? 1 : 0;
    int fc = ((t & 3) == 3 && seg[t] == 0x3f) ? 1 : 0;
    if (nz) atomicAdd(&cdet[0], 1);
    if (fc) atomicAdd(&cdet[1], 1);
  }
  __syncthreads();
  int lay = (cdet[1] > 8) ? 2 : ((cdet[0] > 4) ? 1 : 0);
  auto getb = [&](const unsigned char* p, int i) -> int {
    if (lay == 1) return p[i] != 0;
    if (lay == 2) return ((const float*)p)[i] != 0.f;
    return ((const int*)p)[i] != 0;
  };
  int base = t * 8;
  int spv[8], sgv[8], npv[8], fv[8];
  int a = 0, b = 0, mw = 0, ms = 0, fs = 0;
  for (int j = 0; j < 8; j++) {
    int i = base + j;
    spv[j] = getb(spc, i);
    sgv[j] = 1 - getb(seg, i);
    npv[j] = (tokens[i] != 127) ? 1 : 0;
    fv[j] = spv[j] & sgv[j] & npv[j];
    a += spv[j]; b += sgv[j]; fs += fv[j];
    if (i >= 1 && spv[j]) mw = (i + 1 > mw) ? i + 1 : mw;
    if (i >= 1 && sgv[j]) ms = (i + 1 > ms) ? i + 1 : ms;
  }
  ssp[t + 1] = a; ssg[t + 1] = b; smw[t + 1] = mw; sms[t + 1] = ms; sfl[t + 1] = fs;
  if (t == 0) { ssp[0] = 0; ssg[0] = 0; smw[0] = 0; sms[0] = 0; sfl[0] = 0; }
  __syncthreads();
  for (int off = 1; off < 256; off <<= 1) {
    int v0 = 0, v1 = 0, v2 = 0, v3 = 0, v4 = 0;
    if (t + 1 > off) { v0 = ssp[t+1-off]; v1 = ssg[t+1-off]; v2 = smw[t+1-off]; v3 = sms[t+1-off]; v4 = sfl[t+1-off]; }
    __syncthreads();
    ssp[t + 1] += v0; ssg[t + 1] += v1;
    if (v2 > smw[t + 1]) smw[t + 1] = v2;
    if (v3 > sms[t + 1]) sms[t + 1] = v3;
    sfl[t + 1] += v4;
    __syncthreads();
  }
  if ((t & 3) == 0) {
    int ws = smw[t], ss = sms[t];
    ns64[t >> 2] = ws < ss ? ws : ss;
  }
  int esp = ssp[t], esg = ssg[t], ef = sfl[t];
  for (int j = 0; j < 8; j++) {
    int i = base + j;
    int wint = (i == 0) ? (1 + spv[j]) : (1 + esp);
    int sint = (i == 0) ? (1 + sgv[j]) : (1 + esg);
    mi[i] = make_int4(npv[j] | (spv[j] << 1) | (sgv[j] << 2), wint, sint, 0);
    fpre[i] = ef;
    int lqv = (fv[j] && ef < LCAP) ? ef : -1;
    lq[i] = lqv;
    if (lqv >= 0) atomicOr(&lmk[i >> 6], 1ull << (i & 63));
    esp += spv[j]; esg += sgv[j]; ef += fv[j];
  }
  __syncthreads();
  if (t < 32) lmask[t] = lmk[t];
  if (t < 64) {
    int nsTile = ns64[t] >> 5;           // 32-kv tile index
    int lc = fpre[nsTile * 32];          // landmarks strictly below near zone
    if (lc > LCAP) lc = LCAP;
    smeta[t] = make_int2(nsTile, lc);
  }
}

// ---------------- full mask bit table: cmask[word][q], word=kv/32 ----------------
__global__ __launch_bounds__(256) void bitgen(const int4* __restrict__ mi,
                                              unsigned* __restrict__ cmask) {
  __shared__ int4 km[32];
  int w = blockIdx.x;
  int t = threadIdx.x;
  int q = blockIdx.y * 256 + t;
  if (t < 32) km[t] = mi[w * 32 + t];
  __syncthreads();
  int4 mq = mi[q];
  unsigned word = 0;
  #pragma unroll
  for (int j = 0; j < 32; j++) {
    int kv = w * 32 + j;
    int4 mk = km[j];
    bool v = ((mq.x & mk.x) & 1) &&
             ((mk.x & 2) || (mq.y == mk.y)) &&
             ((mk.x & 4) || (mq.z == mk.z)) &&
             (kv <= q);
    word |= (v ? 1u : 0u) << j;
  }
  cmask[(size_t)w * S + q] = word;
}

// ---------------- embedding gather -> bf16 hb + vtb tiles + landmark copies ----------------
__global__ __launch_bounds__(256) void embedT2(const int* __restrict__ tokens,
                                               const float* __restrict__ emb,
                                               const int* __restrict__ lq,
                                               const unsigned long long* __restrict__ lmask,
                                               bf16_t* __restrict__ hb, bf16_t* __restrict__ vtb,
                                               bf16_t* __restrict__ hbL, bf16_t* __restrict__ vtbL) {
  __shared__ bf16_t tile[64 * 136];
  int tid = threadIdx.x;
  int q0 = blockIdx.x * 64, h = blockIdx.y;
  int ql = tid >> 2, d0 = (tid & 3) * 32;
  int tok = tokens[q0 + ql];
  const float4* src = (const float4*)(emb + (size_t)tok * HID + h * DH + d0);
  bf16x8 ob[4];
  #pragma unroll
  for (int i = 0; i < 8; i++) {
    float4 f = src[i];
    ob[i >> 1][(i & 1) * 4 + 0] = (bf16_t)f.x;
    ob[i >> 1][(i & 1) * 4 + 1] = (bf16_t)f.y;
    ob[i >> 1][(i & 1) * 4 + 2] = (bf16_t)f.z;
    ob[i >> 1][(i & 1) * 4 + 3] = (bf16_t)f.w;
  }
  #pragma unroll
  for (int i = 0; i < 4; i++)
    *(bf16x8*)(hb + (size_t)(q0 + ql) * HID + h * DH + d0 + i * 8) = ob[i];
  #pragma unroll
  for (int i = 0; i < 4; i++)
    #pragma unroll
    for (int j = 0; j < 8; j++) tile[ql * 136 + d0 + i * 8 + j] = ob[i][j];
  __syncthreads();
  {
    int tl = tid >> 7, d = tid & 127;
    bf16_t* vt = vtb + ((size_t)(h * 64) + 2 * blockIdx.x + tl) * 4096;
    #pragma unroll
    for (int c = 0; c < 4; c++) {
      bf16x8 v;
      #pragma unroll
      for (int e = 0; e < 8; e++)
        v[e] = tile[(32 * tl + 8 * (c ^ (d & 3)) + e) * 136 + d];
      *(bf16x8*)(vt + d * 32 + c * 8) = v;
    }
  }
  unsigned long long lm = lmask[q0 >> 6];
  while (lm) {
    int r = __builtin_ctzll(lm);
    lm &= lm - 1;
    int li = lq[q0 + r];
    if (li >= 0 && tid < 128) {
      bf16_t vv = tile[r * 136 + tid];
      hbL[(size_t)li * HID + h * DH + tid] = vv;
      vtbL[((size_t)(h * 4) + (li >> 5)) * 4096 + tid * 32 + (((li & 31) >> 3) ^ (tid & 3)) * 8 + (li & 7)] = vv;
    }
  }
}

// ---------------- fused attention layer: 1 wave / 32-q stripe, barrier-free, tiled V ----------------
__global__ __launch_bounds__(64, 2) void attn8(const bf16_t* __restrict__ hb,
                                               const bf16_t* __restrict__ vtb,
                                               const bf16_t* __restrict__ hbL,
                                               const bf16_t* __restrict__ vtbL,
                                               const unsigned* __restrict__ cmask,
                                               const int4* __restrict__ mi,
                                               const int2* __restrict__ smeta,
                                               const int* __restrict__ lq,
                                               const unsigned long long* __restrict__ lmask,
                                               bf16_t* __restrict__ ob,
                                               bf16_t* __restrict__ ovtb,
                                               bf16_t* __restrict__ obL,
                                               bf16_t* __restrict__ ovtbL,
                                               int writeT) {
  __shared__ __align__(16) char lds_raw[32768];   // 2 bufs x (K 8KB + Vt 8KB)

  int h = blockIdx.x, st = blockIdx.y;            // st 0..63, 32 q each
  int2 sm = smeta[st];
  int nsT = sm.x, lcount = sm.y;
  int nNear = st + 1 - nsT;
  int nLT = (lcount + 31) >> 5;
  int nIter = nNear + nLT;

  int l = threadIdx.x, l31 = l & 31, hi = l >> 5;
  int q0 = 32 * st, q = q0 + l31;
  int npq = mi[q].x & 1;

  bf16x8 qf[8];
  {
    const bf16_t* hq = hb + (size_t)q * HID + h * DH;
    #pragma unroll
    for (int ks = 0; ks < 8; ks++) qf[ks] = *(const bf16x8*)(hq + ks * 16 + hi * 8);
  }

  f32x16 acc[4];
  #pragma unroll
  for (int i = 0; i < 4; i++)
    #pragma unroll
    for (int r = 0; r < 16; r++) acc[i][r] = 0.f;
  float m = -1e30f, lsum = 0.f;
  int swz = l31 & 7;

  auto STAGE = [&](int i, int b) {
    const bf16_t* Kbase; const bf16_t* Vtile;
    if (i < nNear) {
      int t = nsT + i;
      Kbase = hb + (size_t)(t * 32) * HID + h * DH;
      Vtile = vtb + ((size_t)(h * 64) + t) * 4096;
    } else {
      int j = i - nNear;
      Kbase = hbL + (size_t)(j * 32) * HID + h * DH;
      Vtile = vtbL + ((size_t)(h * 4) + j) * 4096;
    }
    bf16_t* Kb = (bf16_t*)(lds_raw + b * 16384);
    bf16_t* Vb = (bf16_t*)(lds_raw + b * 16384 + 8192);
    #pragma unroll
    for (int i2 = 0; i2 < 8; i2++) {
      int rowK = i2 * 4 + (l >> 4); int chK = (l & 15) ^ (rowK & 7);
      gl_lds16(Kbase + (size_t)rowK * HID + chK * 8, Kb + i2 * 512);
    }
    #pragma unroll
    for (int i2 = 0; i2 < 8; i2++)
      gl_lds16(Vtile + i2 * 512 + l * 8, Vb + i2 * 512);
  };

  auto getmask = [&](int i) -> unsigned {
    if (i < nNear) return cmask[(size_t)(nsT + i) * S + q];
    int rem = lcount - (i - nNear) * 32;
    unsigned w0 = (rem >= 32) ? 0xffffffffu : ((rem <= 0) ? 0u : ((1u << rem) - 1u));
    return npq ? w0 : 0u;
  };

  STAGE(0, 0);
  for (int i = 0; i < nIter; i++) {
    int b = i & 1;
    if (i + 1 < nIter) {
      STAGE(i + 1, b ^ 1);
      asm volatile("s_waitcnt vmcnt(16)" ::: "memory");
    } else {
      asm volatile("s_waitcnt vmcnt(0)" ::: "memory");
    }
    unsigned w0 = getmask(i);

    if (__any(w0 != 0u)) {
      const bf16_t* Kb = (const bf16_t*)(lds_raw + b * 16384);
      const bf16_t* Vb = (const bf16_t*)(lds_raw + b * 16384 + 8192);
      // QK^T: two independent 4-deep MFMA chains (ILP), merged after
      f32x16 sA, sB;
      #pragma unroll
      for (int r = 0; r < 16; r++) { sA[r] = 0.f; sB[r] = 0.f; }
      const bf16_t* kp = Kb + l31 * 128;
      #pragma unroll
      for (int ks = 0; ks < 8; ks += 2) {
        bf16x8 kf0 = *(const bf16x8*)(kp + (((2 * ks + hi) ^ swz) * 8));
        bf16x8 kf1 = *(const bf16x8*)(kp + (((2 * (ks + 1) + hi) ^ swz) * 8));
        sA = MFMA32(kf0, qf[ks], sA, 0, 0, 0);
        sB = MFMA32(kf1, qf[ks + 1], sB, 0, 0, 0);
      }

      float sv[16];
      #pragma unroll
      for (int r = 0; r < 16; r++) {
        int bit = (r & 3) + 8 * (r >> 2) + 4 * hi;
        float sr = sA[r] + sB[r];
        sv[r] = ((w0 >> bit) & 1u) ? sr : NEGS;
      }
      // tree max (depth 4)
      float t0 = fmaxf(fmaxf(sv[0], sv[1]), fmaxf(sv[2], sv[3]));
      float t1 = fmaxf(fmaxf(sv[4], sv[5]), fmaxf(sv[6], sv[7]));
      float t2 = fmaxf(fmaxf(sv[8], sv[9]), fmaxf(sv[10], sv[11]));
      float t3 = fmaxf(fmaxf(sv[12], sv[13]), fmaxf(sv[14], sv[15]));
      float mx = fmaxf(fmaxf(t0, t1), fmaxf(t2, t3));
      mx = fmaxf(mx, __shfl_xor(mx, 32, 64));
      if (__any(mx > m + RTHR)) {
        float mn = fmaxf(m, mx);
        float al = exp2f((m - mn) * K2EXP);
        m = mn; lsum *= al;
        #pragma unroll
        for (int r = 0; r < 16; r++) {
          float alr = __shfl(al, (r & 3) + 8 * (r >> 2) + 4 * hi, 64);
          #pragma unroll
          for (int d = 0; d < 4; d++) acc[d][r] *= alr;
        }
      }
      float mk = m * K2EXP;
      float p[16];
      #pragma unroll
      for (int r = 0; r < 16; r++)
        p[r] = exp2f(__builtin_fmaf(sv[r], K2EXP, -mk));
      // tree sum (depth 4)
      float u0 = (p[0] + p[1]) + (p[2] + p[3]);
      float u1 = (p[4] + p[5]) + (p[6] + p[7]);
      float u2 = (p[8] + p[9]) + (p[10] + p[11]);
      float u3 = (p[12] + p[13]) + (p[14] + p[15]);
      float ps = (u0 + u1) + (u2 + u3);
      ps += __shfl_xor(ps, 32, 64);
      lsum += ps;

      bf16x8 pa[2];
      {
        unsigned a0 = cvtpk(p[0], p[1]),   a1 = cvtpk(p[2], p[3]);
        unsigned b0 = cvtpk(p[4], p[5]),   b1 = cvtpk(p[6], p[7]);
        unsigned a2 = cvtpk(p[8], p[9]),   a3 = cvtpk(p[10], p[11]);
        unsigned b2 = cvtpk(p[12], p[13]), b3 = cvtpk(p[14], p[15]);
        plswap(a0, b0); plswap(a1, b1); plswap(a2, b2); plswap(a3, b3);
        pa[0] = mk8(a0, a1, b0, b1);
        pa[1] = mk8(a2, a3, b2, b3);
      }

      #pragma unroll
      for (int db = 0; db < 4; db++) {
        const bf16_t* vr = Vb + (32 * db + l31) * 32;
        #pragma unroll
        for (int ks = 0; ks < 2; ks++) {
          bf16x8 vf = *(const bf16x8*)(vr + (((2 * ks + hi) ^ (l31 & 3)) * 8));
          acc[db] = MFMA32(pa[ks], vf, acc[db], 0, 0, 0);
        }
      }
    }
  }

  // epilogue (single wave, DS ops wave-ordered: no barriers)
  bf16_t* tl = (bf16_t*)lds_raw;   // 32 x 132 bf16
  float inv = (lsum > 0.f) ? 1.f / lsum : 0.f;
  #pragma unroll
  for (int r = 0; r < 16; r++) {
    int qr = (r & 3) + 8 * (r >> 2) + 4 * hi;
    float ivr = __shfl(inv, qr, 64);
    #pragma unroll
    for (int db = 0; db < 4; db++)
      tl[qr * 132 + db * 32 + l31] = (bf16_t)(acc[db][r] * ivr);
  }
  {
    int c4 = l & 3;
    #pragma unroll
    for (int g = 0; g < 2; g++) {
      int row = g * 16 + (l >> 2);
      #pragma unroll
      for (int k = 0; k < 4; k++) {
        bf16x8 v = *(const bf16x8*)(tl + row * 132 + c4 * 32 + k * 8);
        *(bf16x8*)(ob + (size_t)(q0 + row) * HID + h * DH + c4 * 32 + k * 8) = v;
      }
    }
  }
  if (writeT) {
    bf16_t* vt = ovtb + ((size_t)(h * 64) + st) * 4096;
    #pragma unroll
    for (int s = 0; s < 8; s++) {
      int d = s * 16 + (l >> 2);
      bf16x8 v;
      #pragma unroll
      for (int e = 0; e < 8; e++)
        v[e] = tl[(8 * ((l & 3) ^ (d & 3)) + e) * 132 + d];
      *(bf16x8*)(vt + s * 512 + l * 8) = v;
    }
    unsigned lm32 = (unsigned)(lmask[st >> 1] >> ((st & 1) * 32));
    while (lm32) {
      int r = __builtin_ctz(lm32);
      lm32 &= lm32 - 1;
      int li = lq[q0 + r];
      if (li >= 0) {
        #pragma unroll
        for (int half = 0; half < 2; half++) {
          int dd = l + 64 * half;
          bf16_t vv = tl[r * 132 + dd];
          obL[(size_t)li * HID + h * DH + dd] = vv;
          ovtbL[((size_t)(h * 4) + (li >> 5)) * 4096 + dd * 32 + (((li & 31) >> 3) ^ (dd & 3)) * 8 + (li & 7)] = vv;
        }
      }
    }
  }
}

// ---------------- lm head weight convert ----------------
__global__ __launch_bounds__(256) void wcvt(const float* __restrict__ w, bf16_t* __restrict__ wb) {
  int i = blockIdx.x * 256 + threadIdx.x;
  float4 f = ((const float4*)w)[i];
  bf16x4 v;
  v[0] = (bf16_t)f.x; v[1] = (bf16_t)f.y; v[2] = (bf16_t)f.z; v[3] = (bf16_t)f.w;
  *(bf16x4*)(wb + (size_t)i * 4) = v;
}

// ---------------- lm head + segment head fused ----------------
__global__ __launch_bounds__(256) void lmseg_head(const bf16_t* __restrict__ hb,
                                                  const bf16_t* __restrict__ wbf,
                                                  const float* __restrict__ bias,
                                                  const float* __restrict__ sw,
                                                  const float* __restrict__ sb,
                                                  float* __restrict__ out,
                                                  float* __restrict__ outseg) {
  __shared__ float red[4][16][130];
  int tid = threadIdx.x;
  int w = tid >> 6, l = tid & 63, l16 = l & 15, g = l >> 4;
  int t0 = blockIdx.x * 16;
  f32x4 acc[8];
  #pragma unroll
  for (int i = 0; i < 8; i++) acc[i] = (f32x4){0.f, 0.f, 0.f, 0.f};
  const bf16_t* arow = hb + (size_t)(t0 + l16) * HID + w * 512;
  for (int k0 = 0; k0 < 512; k0 += 32) {
    bf16x8 af = *(const bf16x8*)(arow + k0 + g * 8);
    #pragma unroll
    for (int vt = 0; vt < 8; vt++) {
      bf16x8 bf_ = *(const bf16x8*)(wbf + (size_t)(vt * 16 + l16) * HID + w * 512 + k0 + g * 8);
      acc[vt] = MFMA16(af, bf_, acc[vt], 0, 0, 0);
    }
  }
  #pragma unroll
  for (int vt = 0; vt < 8; vt++)
    #pragma unroll
    for (int r = 0; r < 4; r++)
      red[w][4 * g + r][vt * 16 + l16] = acc[vt][r];
  __syncthreads();
  int q = tid >> 4, vc = (tid & 15) * 8;
  #pragma unroll
  for (int j = 0; j < 8; j++) {
    float s = red[0][q][vc + j] + red[1][q][vc + j] + red[2][q][vc + j] + red[3][q][vc + j];
    out[(size_t)(t0 + q) * VOC + vc + j] = s + bias[vc + j];
  }
  {
    int c = tid & 15;
    const bf16_t* hrow = hb + (size_t)(t0 + q) * HID + c * 128;
    float s0 = 0.f, s1 = 0.f;
    #pragma unroll
    for (int i = 0; i < 16; i++) {
      bf16x8 v = *(const bf16x8*)(hrow + i * 8);
      const float4* w0p = (const float4*)(sw + c * 128 + i * 8);
      const float4* w1p = (const float4*)(sw + HID + c * 128 + i * 8);
      float4 x0 = w0p[0], x1 = w0p[1], y0 = w1p[0], y1 = w1p[1];
      s0 += (float)v[0]*x0.x + (float)v[1]*x0.y + (float)v[2]*x0.z + (float)v[3]*x0.w
          + (float)v[4]*x1.x + (float)v[5]*x1.y + (float)v[6]*x1.z + (float)v[7]*x1.w;
      s1 += (float)v[0]*y0.x + (float)v[1]*y0.y + (float)v[2]*y0.z + (float)v[3]*y0.w
          + (float)v[4]*y1.x + (float)v[5]*y1.y + (float)v[6]*y1.z + (float)v[7]*y1.w;
    }
    #pragma unroll
    for (int off = 1; off < 16; off <<= 1) {
      s0 += __shfl_xor(s0, off, 64);
      s1 += __shfl_xor(s1, off, 64);
    }
    if (c == 0) {
      outseg[(size_t)(t0 + q) * 2] = s0 + sb[0];
      outseg[(size_t)(t0 + q) * 2 + 1] = s1 + sb[1];
    }
  }
}

extern "C" void kernel_launch(void* const* d_in, const int* in_sizes, int n_in,
                              void* d_out, int out_size, void* d_ws, size_t ws_size,
                              hipStream_t stream) {
  const int* tokens = (const int*)d_in[0];
  const unsigned char* seg = (const unsigned char*)d_in[1];
  const unsigned char* spc = (const unsigned char*)d_in[2];
  const float* emb_w = (const float*)d_in[3];
  const float* lm_w = (const float*)d_in[4];
  const float* lm_b = (const float*)d_in[5];
  const float* seg_w = (const float*)d_in[6];
  const float* seg_b = (const float*)d_in[7];

  char* ws = (char*)d_ws;
  int4* mi = (int4*)ws;                                              // 32KB @0
  unsigned* cmask = (unsigned*)(ws + (1u << 20));                    // 512KB @1MB
  int* lq = (int*)(ws + (1u << 20) + (512u << 10));                  // 8KB
  unsigned long long* lmask = (unsigned long long*)(ws + (1u << 20) + (520u << 10)); // 256B
  int2* smeta = (int2*)(ws + (1u << 20) + (524u << 10));             // 512B
  bf16_t* wbf = (bf16_t*)(ws + (2u << 20));                          // 512KB @2MB
  bf16_t* hbLA  = (bf16_t*)(ws + (3u << 20));                        // 512KB @3MB
  bf16_t* hbLB  = (bf16_t*)(ws + (3u << 20) + (512u << 10));         // 512KB
  bf16_t* vtbLA = (bf16_t*)(ws + (4u << 20));                        // 512KB @4MB
  bf16_t* vtbLB = (bf16_t*)(ws + (4u << 20) + (512u << 10));         // 512KB
  bf16_t* hbA  = (bf16_t*)(ws + (8u << 20));                         // 8MB @8MB
  bf16_t* hbB  = (bf16_t*)(ws + (16u << 20));                        // 8MB @16MB
  bf16_t* vtbA = (bf16_t*)(ws + (24u << 20));                        // 8MB @24MB
  bf16_t* vtbB = (bf16_t*)(ws + (32u << 20));                        // 8MB @32MB
  float* out = (float*)d_out;

  maskprep2<<<1, 256, 0, stream>>>(tokens, seg, spc, mi, lq, lmask, smeta);
  bitgen<<<dim3(64, 8), 256, 0, stream>>>(mi, cmask);
  embedT2<<<dim3(S / 64, NH), 256, 0, stream>>>(tokens, emb_w, lq, lmask, hbA, vtbA, hbLA, vtbLA);

  bf16_t* cur = hbA;   bf16_t* curV = vtbA;
  bf16_t* nxt = hbB;   bf16_t* nxtV = vtbB;
  bf16_t* curL = hbLA; bf16_t* curLV = vtbLA;
  bf16_t* nxtL = hbLB; bf16_t* nxtLV = vtbLB;
  for (int L = 0; L < 4; L++) {
    attn8<<<dim3(NH, 64), 64, 0, stream>>>(cur, curV, curL, curLV, cmask, mi, smeta, lq, lmask,
                                           nxt, nxtV, nxtL, nxtLV, (L < 3) ? 1 : 0);
    bf16_t* t1 = cur; cur = nxt; nxt = t1;
    bf16_t* t2 = curV; curV = nxtV; nxtV = t2;
    bf16_t* t3 = curL; curL = nxtL; nxtL = t3;
    bf16_t* t4 = curLV; curLV = nxtLV; nxtLV = t4;
  }

  wcvt<<<(VOC * HID / 4) / 256, 256, 0, stream>>>(lm_w, wbf);
  lmseg_head<<<S / 16, 256, 0, stream>>>(cur, wbf, lm_b, seg_w, seg_b, out, out + (size_t)S * VOC);
}

// Round 14
// 121.717 us; speedup vs baseline: 3.8098x; 1.1302x over previous
//
#include <hip/hip_runtime.h>

#define S 2048
#define HID 2048
#define NH 16
#define DH 128
#define VOC 128
#define LCAP 128
#define K2EXP 0.12752551286084112f   // (1/sqrt(128)) * log2(e)
#define RTHR 62.0f                   // defer-max threshold in raw-score units
#define NEGS -3.0e38f

typedef __bf16 bf16_t;
typedef __attribute__((ext_vector_type(8))) __bf16 bf16x8;
typedef __attribute__((ext_vector_type(4))) __bf16 bf16x4;
typedef __attribute__((ext_vector_type(4))) float f32x4;
typedef __attribute__((ext_vector_type(16))) float f32x16;

typedef __attribute__((address_space(1))) unsigned int guint;
typedef __attribute__((address_space(3))) unsigned int luint;

#define MFMA16 __builtin_amdgcn_mfma_f32_16x16x32_bf16
#define MFMA32 __builtin_amdgcn_mfma_f32_32x32x16_bf16

__device__ __forceinline__ void gl_lds16(const void* g, void* l) {
  __builtin_amdgcn_global_load_lds((guint*)(unsigned long long)g,
                                   (luint*)(unsigned)(unsigned long long)l,
                                   16, 0, 0);
}

__device__ __forceinline__ unsigned cvtpk(float lo, float hi) {
  unsigned r;
  asm("v_cvt_pk_bf16_f32 %0, %1, %2" : "=v"(r) : "v"(lo), "v"(hi));
  return r;
}
__device__ __forceinline__ void plswap(unsigned& a, unsigned& b) {
  asm volatile("v_permlane32_swap_b32 %0, %1" : "+v"(a), "+v"(b));
}
__device__ __forceinline__ bf16x8 mk8(unsigned d0, unsigned d1, unsigned d2, unsigned d3) {
  union { unsigned u[4]; bf16x8 v; } x;
  x.u[0] = d0; x.u[1] = d1; x.u[2] = d2; x.u[3] = d3;
  return x.v;
}

// Tile layouts (per head h, 32-kv tile t; contiguous 4096 halfwords = 8KB):
//  ktb[(h*64+t)*4096 + row*128 + c*8 + e] = hid[32t+row][h*DH + 8*(c^(row&7)) + e]
//  vtb[(h*64+t)*4096 + d*32   + c*8 + e] = hid[32t + 8*(c^(d&3)) + e][h*DH + d]
// Both are verbatim images of the LDS staging tiles -> 8x 1KB coalesced loads/stores.

// ---------------- mask precompute: intervals + starts + landmarks + 32q-stripe meta ----------------
__global__ __launch_bounds__(256) void maskprep2(const int* __restrict__ tokens,
                                                 const unsigned char* __restrict__ seg,
                                                 const unsigned char* __restrict__ spc,
                                                 int4* __restrict__ mi,
                                                 int* __restrict__ lq,
                                                 unsigned long long* __restrict__ lmask,
                                                 int2* __restrict__ smeta) {
  __shared__ int ssp[257], ssg[257], smw[257], sms[257], sfl[257];
  __shared__ int fpre[2048];
  __shared__ int ns64[64];
  __shared__ unsigned long long lmk[32];
  __shared__ int cdet[2];
  int t = threadIdx.x;
  if (t < 2) cdet[t] = 0;
  if (t < 32) lmk[t] = 0ull;
  __syncthreads();
  {
    int nz = ((t & 3) != 0 && seg[t]) ? 1 : 0;
    int fc = ((t & 3) == 3 && seg[t] == 0x3f) ? 1 : 0;
    if (nz) atomicAdd(&cdet[0], 1);
    if (fc) atomicAdd(&cdet[1], 1);
  }
  __syncthreads();
  int lay = (cdet[1] > 8) ? 2 : ((cdet[0] > 4) ? 1 : 0);
  auto getb = [&](const unsigned char* p, int i) -> int {
    if (lay == 1) return p[i] != 0;
    if (lay == 2) return ((const float*)p)[i] != 0.f;
    return ((const int*)p)[i] != 0;
  };
  int base = t * 8;
  int spv[8], sgv[8], npv[8], fv[8];
  int a = 0, b = 0, mw = 0, ms = 0, fs = 0;
  for (int j = 0; j < 8; j++) {
    int i = base + j;
    spv[j] = getb(spc, i);
    sgv[j] = 1 - getb(seg, i);
    npv[j] = (tokens[i] != 127) ? 1 : 0;
    fv[j] = spv[j] & sgv[j] & npv[j];
    a += spv[j]; b += sgv[j]; fs += fv[j];
    if (i >= 1 && spv[j]) mw = (i + 1 > mw) ? i + 1 : mw;
    if (i >= 1 && sgv[j]) ms = (i + 1 > ms) ? i + 1 : ms;
  }
  ssp[t + 1] = a; ssg[t + 1] = b; smw[t + 1] = mw; sms[t + 1] = ms; sfl[t + 1] = fs;
  if (t == 0) { ssp[0] = 0; ssg[0] = 0; smw[0] = 0; sms[0] = 0; sfl[0] = 0; }
  __syncthreads();
  for (int off = 1; off < 256; off <<= 1) {
    int v0 = 0, v1 = 0, v2 = 0, v3 = 0, v4 = 0;
    if (t + 1 > off) { v0 = ssp[t+1-off]; v1 = ssg[t+1-off]; v2 = smw[t+1-off]; v3 = sms[t+1-off]; v4 = sfl[t+1-off]; }
    __syncthreads();
    ssp[t + 1] += v0; ssg[t + 1] += v1;
    if (v2 > smw[t + 1]) smw[t + 1] = v2;
    if (v3 > sms[t + 1]) sms[t + 1] = v3;
    sfl[t + 1] += v4;
    __syncthreads();
  }
  if ((t & 3) == 0) {
    int ws = smw[t], ss = sms[t];
    ns64[t >> 2] = ws < ss ? ws : ss;
  }
  int esp = ssp[t], esg = ssg[t], ef = sfl[t];
  for (int j = 0; j < 8; j++) {
    int i = base + j;
    int wint = (i == 0) ? (1 + spv[j]) : (1 + esp);
    int sint = (i == 0) ? (1 + sgv[j]) : (1 + esg);
    mi[i] = make_int4(npv[j] | (spv[j] << 1) | (sgv[j] << 2), wint, sint, 0);
    fpre[i] = ef;
    int lqv = (fv[j] && ef < LCAP) ? ef : -1;
    lq[i] = lqv;
    if (lqv >= 0) atomicOr(&lmk[i >> 6], 1ull << (i & 63));
    esp += spv[j]; esg += sgv[j]; ef += fv[j];
  }
  __syncthreads();
  if (t < 32) lmask[t] = lmk[t];
  if (t < 64) {
    int nsTile = ns64[t] >> 5;           // 32-kv tile index
    int lc = fpre[nsTile * 32];          // landmarks strictly below near zone
    if (lc > LCAP) lc = LCAP;
    smeta[t] = make_int2(nsTile, lc);
  }
}

// ---------------- megaprep: embed(ktb/vtb/landmarks) + bitgen + wcvt in one launch ----------------
__global__ __launch_bounds__(256) void megaprep(const int* __restrict__ tokens,
                                                const float* __restrict__ emb,
                                                const int4* __restrict__ mi,
                                                const int* __restrict__ lq,
                                                const unsigned long long* __restrict__ lmask,
                                                const float* __restrict__ lm_w,
                                                bf16_t* __restrict__ wbf,
                                                unsigned* __restrict__ cmask,
                                                bf16_t* __restrict__ ktb,
                                                bf16_t* __restrict__ vtb,
                                                bf16_t* __restrict__ ktbL,
                                                bf16_t* __restrict__ vtbL) {
  __shared__ __align__(16) bf16_t tile[64 * 136];
  int bid = blockIdx.x;
  int tid = threadIdx.x;

  if (bid < 512) {
    // ---- embed role: 64 q-rows x head h -> ktb/vtb tiles + landmark tiles ----
    int qblk = bid & 31, h = bid >> 5;
    int q0 = qblk * 64;
    int ql = tid >> 2, d0 = (tid & 3) * 32;
    int tok = tokens[q0 + ql];
    const float4* src = (const float4*)(emb + (size_t)tok * HID + h * DH + d0);
    #pragma unroll
    for (int i = 0; i < 8; i++) {
      float4 f = src[i];
      tile[ql * 136 + d0 + i * 4 + 0] = (bf16_t)f.x;
      tile[ql * 136 + d0 + i * 4 + 1] = (bf16_t)f.y;
      tile[ql * 136 + d0 + i * 4 + 2] = (bf16_t)f.z;
      tile[ql * 136 + d0 + i * 4 + 3] = (bf16_t)f.w;
    }
    __syncthreads();
    // ktb tiles (2 per block)
    {
      int tl2 = tid >> 7, half = (tid >> 6) & 1, lane = tid & 63;
      bf16_t* kt = ktb + ((size_t)(h * 64) + 2 * qblk + tl2) * 4096;
      #pragma unroll
      for (int k = 0; k < 4; k++) {
        int s = half * 4 + k;
        int row = s * 4 + (lane >> 4);
        int c = lane & 15;
        bf16x8 v;
        #pragma unroll
        for (int e = 0; e < 8; e++)
          v[e] = tile[(32 * tl2 + row) * 136 + 8 * (c ^ (row & 7)) + e];
        *(bf16x8*)(kt + s * 512 + lane * 8) = v;
      }
    }
    // vtb tiles
    {
      int tl2 = tid >> 7, d = tid & 127;
      bf16_t* vt = vtb + ((size_t)(h * 64) + 2 * qblk + tl2) * 4096;
      #pragma unroll
      for (int c = 0; c < 4; c++) {
        bf16x8 v;
        #pragma unroll
        for (int e = 0; e < 8; e++)
          v[e] = tile[(32 * tl2 + 8 * (c ^ (d & 3)) + e) * 136 + d];
        *(bf16x8*)(vt + d * 32 + c * 8) = v;
      }
    }
    // landmark tiles
    unsigned long long lm = lmask[q0 >> 6];
    while (lm) {
      int r = __builtin_ctzll(lm);
      lm &= lm - 1;
      int li = lq[q0 + r];
      if (li >= 0 && tid < 128) {
        int dd = tid;
        bf16_t vv = tile[r * 136 + dd];
        int row = li & 31, jt = li >> 5;
        ktbL[((size_t)(h * 4) + jt) * 4096 + row * 128 + ((dd >> 3) ^ (row & 7)) * 8 + (dd & 7)] = vv;
        vtbL[((size_t)(h * 4) + jt) * 4096 + dd * 32 + ((row >> 3) ^ (dd & 3)) * 8 + (row & 7)] = vv;
      }
    }
  } else if (bid < 1024) {
    // ---- bitgen role ----
    __shared__ int4 km[32];
    int b2 = bid - 512;
    int w = b2 & 63, y = b2 >> 6;
    int q = y * 256 + tid;
    if (tid < 32) km[tid] = mi[w * 32 + tid];
    __syncthreads();
    int4 mq = mi[q];
    unsigned word = 0;
    #pragma unroll
    for (int j = 0; j < 32; j++) {
      int kv = w * 32 + j;
      int4 mk = km[j];
      bool v = ((mq.x & mk.x) & 1) &&
               ((mk.x & 2) || (mq.y == mk.y)) &&
               ((mk.x & 4) || (mq.z == mk.z)) &&
               (kv <= q);
      word |= (v ? 1u : 0u) << j;
    }
    cmask[(size_t)w * S + q] = word;
  } else {
    // ---- wcvt role ----
    int i = (bid - 1024) * 256 + tid;
    float4 f = ((const float4*)lm_w)[i];
    bf16x4 v;
    v[0] = (bf16_t)f.x; v[1] = (bf16_t)f.y; v[2] = (bf16_t)f.z; v[3] = (bf16_t)f.w;
    *(bf16x4*)(wbf + (size_t)i * 4) = v;
  }
}

// ---------------- fused attention layer: 1 wave / 32-q stripe, barrier-free, tiled K+V ----------------
__global__ __launch_bounds__(64, 2) void attn9(const bf16_t* __restrict__ ktb,
                                               const bf16_t* __restrict__ vtb,
                                               const bf16_t* __restrict__ ktbL,
                                               const bf16_t* __restrict__ vtbL,
                                               const unsigned* __restrict__ cmask,
                                               const int4* __restrict__ mi,
                                               const int2* __restrict__ smeta,
                                               const int* __restrict__ lq,
                                               const unsigned long long* __restrict__ lmask,
                                               bf16_t* __restrict__ oktb,
                                               bf16_t* __restrict__ ovtb,
                                               bf16_t* __restrict__ oktbL,
                                               bf16_t* __restrict__ ovtbL,
                                               bf16_t* __restrict__ hbF,
                                               int writeT) {
  __shared__ __align__(16) char lds_raw[32768];   // 2 bufs x (K 8KB + Vt 8KB)

  int h = blockIdx.x, st = blockIdx.y;            // st 0..63, 32 q each
  int2 sm = smeta[st];
  int nsT = sm.x, lcount = sm.y;
  int nNear = st + 1 - nsT;
  int nLT = (lcount + 31) >> 5;
  int nIter = nNear + nLT;

  int l = threadIdx.x, l31 = l & 31, hi = l >> 5;
  int q0 = 32 * st, q = q0 + l31;
  int npq = mi[q].x & 1;
  int swz = l31 & 7;

  // Q fragments from my own ktb tile (h, st)
  bf16x8 qf[8];
  {
    const bf16_t* kt0 = ktb + ((size_t)(h * 64) + st) * 4096;
    #pragma unroll
    for (int ks = 0; ks < 8; ks++)
      qf[ks] = *(const bf16x8*)(kt0 + l31 * 128 + (((2 * ks + hi) ^ swz) * 8));
  }

  f32x16 acc[4];
  #pragma unroll
  for (int i = 0; i < 4; i++)
    #pragma unroll
    for (int r = 0; r < 16; r++) acc[i][r] = 0.f;
  float m = -1e30f, lsum = 0.f;

  auto STAGE = [&](int i, int b) {
    const bf16_t* Ktile; const bf16_t* Vtile;
    if (i < nNear) {
      int t = nsT + i;
      Ktile = ktb + ((size_t)(h * 64) + t) * 4096;
      Vtile = vtb + ((size_t)(h * 64) + t) * 4096;
    } else {
      int j = i - nNear;
      Ktile = ktbL + ((size_t)(h * 4) + j) * 4096;
      Vtile = vtbL + ((size_t)(h * 4) + j) * 4096;
    }
    bf16_t* Kb = (bf16_t*)(lds_raw + b * 16384);
    bf16_t* Vb = (bf16_t*)(lds_raw + b * 16384 + 8192);
    #pragma unroll
    for (int i2 = 0; i2 < 8; i2++)
      gl_lds16(Ktile + i2 * 512 + l * 8, Kb + i2 * 512);
    #pragma unroll
    for (int i2 = 0; i2 < 8; i2++)
      gl_lds16(Vtile + i2 * 512 + l * 8, Vb + i2 * 512);
  };

  auto getmask = [&](int i) -> unsigned {
    if (i < nNear) return cmask[(size_t)(nsT + i) * S + q];
    int rem = lcount - (i - nNear) * 32;
    unsigned w0 = (rem >= 32) ? 0xffffffffu : ((rem <= 0) ? 0u : ((1u << rem) - 1u));
    return npq ? w0 : 0u;
  };

  STAGE(0, 0);
  for (int i = 0; i < nIter; i++) {
    int b = i & 1;
    if (i + 1 < nIter) {
      STAGE(i + 1, b ^ 1);
      asm volatile("s_waitcnt vmcnt(16)" ::: "memory");
    } else {
      asm volatile("s_waitcnt vmcnt(0)" ::: "memory");
    }
    unsigned w0 = getmask(i);

    if (__any(w0 != 0u)) {
      const bf16_t* Kb = (const bf16_t*)(lds_raw + b * 16384);
      const bf16_t* Vb = (const bf16_t*)(lds_raw + b * 16384 + 8192);
      f32x16 sA, sB;
      #pragma unroll
      for (int r = 0; r < 16; r++) { sA[r] = 0.f; sB[r] = 0.f; }
      const bf16_t* kp = Kb + l31 * 128;
      #pragma unroll
      for (int ks = 0; ks < 8; ks += 2) {
        bf16x8 kf0 = *(const bf16x8*)(kp + (((2 * ks + hi) ^ swz) * 8));
        bf16x8 kf1 = *(const bf16x8*)(kp + (((2 * (ks + 1) + hi) ^ swz) * 8));
        sA = MFMA32(kf0, qf[ks], sA, 0, 0, 0);
        sB = MFMA32(kf1, qf[ks + 1], sB, 0, 0, 0);
      }

      float sv[16];
      #pragma unroll
      for (int r = 0; r < 16; r++) {
        int bit = (r & 3) + 8 * (r >> 2) + 4 * hi;
        float sr = sA[r] + sB[r];
        sv[r] = ((w0 >> bit) & 1u) ? sr : NEGS;
      }
      float t0 = fmaxf(fmaxf(sv[0], sv[1]), fmaxf(sv[2], sv[3]));
      float t1 = fmaxf(fmaxf(sv[4], sv[5]), fmaxf(sv[6], sv[7]));
      float t2 = fmaxf(fmaxf(sv[8], sv[9]), fmaxf(sv[10], sv[11]));
      float t3 = fmaxf(fmaxf(sv[12], sv[13]), fmaxf(sv[14], sv[15]));
      float mx = fmaxf(fmaxf(t0, t1), fmaxf(t2, t3));
      mx = fmaxf(mx, __shfl_xor(mx, 32, 64));
      if (__any(mx > m + RTHR)) {
        float mn = fmaxf(m, mx);
        float al = exp2f((m - mn) * K2EXP);
        m = mn; lsum *= al;
        #pragma unroll
        for (int r = 0; r < 16; r++) {
          float alr = __shfl(al, (r & 3) + 8 * (r >> 2) + 4 * hi, 64);
          #pragma unroll
          for (int d = 0; d < 4; d++) acc[d][r] *= alr;
        }
      }
      float mk = m * K2EXP;
      float p[16];
      #pragma unroll
      for (int r = 0; r < 16; r++)
        p[r] = exp2f(__builtin_fmaf(sv[r], K2EXP, -mk));
      float u0 = (p[0] + p[1]) + (p[2] + p[3]);
      float u1 = (p[4] + p[5]) + (p[6] + p[7]);
      float u2 = (p[8] + p[9]) + (p[10] + p[11]);
      float u3 = (p[12] + p[13]) + (p[14] + p[15]);
      float ps = (u0 + u1) + (u2 + u3);
      ps += __shfl_xor(ps, 32, 64);
      lsum += ps;

      bf16x8 pa[2];
      {
        unsigned a0 = cvtpk(p[0], p[1]),   a1 = cvtpk(p[2], p[3]);
        unsigned b0 = cvtpk(p[4], p[5]),   b1 = cvtpk(p[6], p[7]);
        unsigned a2 = cvtpk(p[8], p[9]),   a3 = cvtpk(p[10], p[11]);
        unsigned b2 = cvtpk(p[12], p[13]), b3 = cvtpk(p[14], p[15]);
        plswap(a0, b0); plswap(a1, b1); plswap(a2, b2); plswap(a3, b3);
        pa[0] = mk8(a0, a1, b0, b1);
        pa[1] = mk8(a2, a3, b2, b3);
      }

      #pragma unroll
      for (int db = 0; db < 4; db++) {
        const bf16_t* vr = Vb + (32 * db + l31) * 32;
        #pragma unroll
        for (int ks = 0; ks < 2; ks++) {
          bf16x8 vf = *(const bf16x8*)(vr + (((2 * ks + hi) ^ (l31 & 3)) * 8));
          acc[db] = MFMA32(pa[ks], vf, acc[db], 0, 0, 0);
        }
      }
    }
  }

  // epilogue (single wave, DS ops wave-ordered: no barriers)
  bf16_t* tl = (bf16_t*)lds_raw;   // 32 x 132 bf16
  float inv = (lsum > 0.f) ? 1.f / lsum : 0.f;
  #pragma unroll
  for (int r = 0; r < 16; r++) {
    int qr = (r & 3) + 8 * (r >> 2) + 4 * hi;
    float ivr = __shfl(inv, qr, 64);
    #pragma unroll
    for (int db = 0; db < 4; db++)
      tl[qr * 132 + db * 32 + l31] = (bf16_t)(acc[db][r] * ivr);
  }
  if (writeT) {
    // ktb tile (h, st): 8 coalesced 1KB segments
    bf16_t* kt = oktb + ((size_t)(h * 64) + st) * 4096;
    #pragma unroll
    for (int s = 0; s < 8; s++) {
      int row = s * 4 + (l >> 4);
      int c = l & 15;
      bf16x8 v;
      #pragma unroll
      for (int e = 0; e < 8; e++)
        v[e] = tl[row * 132 + 8 * (c ^ (row & 7)) + e];
      *(bf16x8*)(kt + s * 512 + l * 8) = v;
    }
    // vtb tile (h, st)
    bf16_t* vt = ovtb + ((size_t)(h * 64) + st) * 4096;
    #pragma unroll
    for (int s = 0; s < 8; s++) {
      int d = s * 16 + (l >> 2);
      bf16x8 v;
      #pragma unroll
      for (int e = 0; e < 8; e++)
        v[e] = tl[(8 * ((l & 3) ^ (d & 3)) + e) * 132 + d];
      *(bf16x8*)(vt + s * 512 + l * 8) = v;
    }
    // landmark rows
    unsigned lm32 = (unsigned)(lmask[st >> 1] >> ((st & 1) * 32));
    while (lm32) {
      int r = __builtin_ctz(lm32);
      lm32 &= lm32 - 1;
      int li = lq[q0 + r];
      if (li >= 0) {
        int row = li & 31, jt = li >> 5;
        #pragma unroll
        for (int half = 0; half < 2; half++) {
          int dd = l + 64 * half;
          bf16_t vv = tl[r * 132 + dd];
          oktbL[((size_t)(h * 4) + jt) * 4096 + row * 128 + ((dd >> 3) ^ (row & 7)) * 8 + (dd & 7)] = vv;
          ovtbL[((size_t)(h * 4) + jt) * 4096 + dd * 32 + ((row >> 3) ^ (dd & 3)) * 8 + (row & 7)] = vv;
        }
      }
    }
  } else {
    // final layer: row-major hidden for the heads kernel
    int c4 = l & 3;
    #pragma unroll
    for (int g = 0; g < 2; g++) {
      int row = g * 16 + (l >> 2);
      #pragma unroll
      for (int k = 0; k < 4; k++) {
        bf16x8 v = *(const bf16x8*)(tl + row * 132 + c4 * 32 + k * 8);
        *(bf16x8*)(hbF + (size_t)(q0 + row) * HID + h * DH + c4 * 32 + k * 8) = v;
      }
    }
  }
}

// ---------------- lm head + segment head fused ----------------
__global__ __launch_bounds__(256) void lmseg_head(const bf16_t* __restrict__ hb,
                                                  const bf16_t* __restrict__ wbf,
                                                  const float* __restrict__ bias,
                                                  const float* __restrict__ sw,
                                                  const float* __restrict__ sb,
                                                  float* __restrict__ out,
                                                  float* __restrict__ outseg) {
  __shared__ float red[4][16][130];
  int tid = threadIdx.x;
  int w = tid >> 6, l = tid & 63, l16 = l & 15, g = l >> 4;
  int t0 = blockIdx.x * 16;
  f32x4 acc[8];
  #pragma unroll
  for (int i = 0; i < 8; i++) acc[i] = (f32x4){0.f, 0.f, 0.f, 0.f};
  const bf16_t* arow = hb + (size_t)(t0 + l16) * HID + w * 512;
  for (int k0 = 0; k0 < 512; k0 += 32) {
    bf16x8 af = *(const bf16x8*)(arow + k0 + g * 8);
    #pragma unroll
    for (int vt = 0; vt < 8; vt++) {
      bf16x8 bf_ = *(const bf16x8*)(wbf + (size_t)(vt * 16 + l16) * HID + w * 512 + k0 + g * 8);
      acc[vt] = MFMA16(af, bf_, acc[vt], 0, 0, 0);
    }
  }
  #pragma unroll
  for (int vt = 0; vt < 8; vt++)
    #pragma unroll
    for (int r = 0; r < 4; r++)
      red[w][4 * g + r][vt * 16 + l16] = acc[vt][r];
  __syncthreads();
  int q = tid >> 4, vc = (tid & 15) * 8;
  #pragma unroll
  for (int j = 0; j < 8; j++) {
    float s = red[0][q][vc + j] + red[1][q][vc + j] + red[2][q][vc + j] + red[3][q][vc + j];
    out[(size_t)(t0 + q) * VOC + vc + j] = s + bias[vc + j];
  }
  {
    int c = tid & 15;
    const bf16_t* hrow = hb + (size_t)(t0 + q) * HID + c * 128;
    float s0 = 0.f, s1 = 0.f;
    #pragma unroll
    for (int i = 0; i < 16; i++) {
      bf16x8 v = *(const bf16x8*)(hrow + i * 8);
      const float4* w0p = (const float4*)(sw + c * 128 + i * 8);
      const float4* w1p = (const float4*)(sw + HID + c * 128 + i * 8);
      float4 x0 = w0p[0], x1 = w0p[1], y0 = w1p[0], y1 = w1p[1];
      s0 += (float)v[0]*x0.x + (float)v[1]*x0.y + (float)v[2]*x0.z + (float)v[3]*x0.w
          + (float)v[4]*x1.x + (float)v[5]*x1.y + (float)v[6]*x1.z + (float)v[7]*x1.w;
      s1 += (float)v[0]*y0.x + (float)v[1]*y0.y + (float)v[2]*y0.z + (float)v[3]*y0.w
          + (float)v[4]*y1.x + (float)v[5]*y1.y + (float)v[6]*y1.z + (float)v[7]*y1.w;
    }
    #pragma unroll
    for (int off = 1; off < 16; off <<= 1) {
      s0 += __shfl_xor(s0, off, 64);
      s1 += __shfl_xor(s1, off, 64);
    }
    if (c == 0) {
      outseg[(size_t)(t0 + q) * 2] = s0 + sb[0];
      outseg[(size_t)(t0 + q) * 2 + 1] = s1 + sb[1];
    }
  }
}

extern "C" void kernel_launch(void* const* d_in, const int* in_sizes, int n_in,
                              void* d_out, int out_size, void* d_ws, size_t ws_size,
                              hipStream_t stream) {
  const int* tokens = (const int*)d_in[0];
  const unsigned char* seg = (const unsigned char*)d_in[1];
  const unsigned char* spc = (const unsigned char*)d_in[2];
  const float* emb_w = (const float*)d_in[3];
  const float* lm_w = (const float*)d_in[4];
  const float* lm_b = (const float*)d_in[5];
  const float* seg_w = (const float*)d_in[6];
  const float* seg_b = (const float*)d_in[7];

  char* ws = (char*)d_ws;
  int4* mi = (int4*)ws;                                              // 32KB @0
  unsigned* cmask = (unsigned*)(ws + (1u << 20));                    // 512KB @1MB
  int* lq = (int*)(ws + (1u << 20) + (512u << 10));                  // 8KB
  unsigned long long* lmask = (unsigned long long*)(ws + (1u << 20) + (520u << 10)); // 256B
  int2* smeta = (int2*)(ws + (1u << 20) + (524u << 10));             // 512B
  bf16_t* wbf = (bf16_t*)(ws + (2u << 20));                          // 512KB @2MB
  bf16_t* ktbLA = (bf16_t*)(ws + (3u << 20));                        // 512KB @3MB
  bf16_t* ktbLB = (bf16_t*)(ws + (3u << 20) + (512u << 10));         // 512KB
  bf16_t* vtbLA = (bf16_t*)(ws + (4u << 20));                        // 512KB @4MB
  bf16_t* vtbLB = (bf16_t*)(ws + (4u << 20) + (512u << 10));         // 512KB
  bf16_t* hbF  = (bf16_t*)(ws + (8u << 20));                         // 8MB @8MB
  bf16_t* ktbA = (bf16_t*)(ws + (16u << 20));                        // 8MB @16MB
  bf16_t* ktbB = (bf16_t*)(ws + (24u << 20));                        // 8MB @24MB
  bf16_t* vtbA = (bf16_t*)(ws + (32u << 20));                        // 8MB @32MB
  bf16_t* vtbB = (bf16_t*)(ws + (40u << 20));                        // 8MB @40MB
  float* out = (float*)d_out;

  maskprep2<<<1, 256, 0, stream>>>(tokens, seg, spc, mi, lq, lmask, smeta);
  megaprep<<<1280, 256, 0, stream>>>(tokens, emb_w, mi, lq, lmask, lm_w, wbf, cmask,
                                     ktbA, vtbA, ktbLA, vtbLA);

  bf16_t* curK = ktbA;  bf16_t* curV = vtbA;
  bf16_t* nxtK = ktbB;  bf16_t* nxtV = vtbB;
  bf16_t* curKL = ktbLA; bf16_t* curVL = vtbLA;
  bf16_t* nxtKL = ktbLB; bf16_t* nxtVL = vtbLB;
  for (int L = 0; L < 4; L++) {
    attn9<<<dim3(NH, 64), 64, 0, stream>>>(curK, curV, curKL, curVL, cmask, mi, smeta, lq, lmask,
                                           nxtK, nxtV, nxtKL, nxtVL, hbF, (L < 3) ? 1 : 0);
    bf16_t* t1 = curK; curK = nxtK; nxtK = t1;
    bf16_t* t2 = curV; curV = nxtV; nxtV = t2;
    bf16_t* t3 = curKL; curKL = nxtKL; nxtKL = t3;
    bf16_t* t4 = curVL; curVL = nxtVL; nxtVL = t4;
  }

  lmseg_head<<<S / 16, 256, 0, stream>>>(hbF, wbf, lm_b, seg_w, seg_b, out, out + (size_t)S * VOC);
}

// Round 15
// 119.546 us; speedup vs baseline: 3.8790x; 1.0182x over previous
//
#include <hip/hip_runtime.h>

#define S 2048
#define HID 2048
#define NH 16
#define DH 128
#define VOC 128
#define LCAP 128
#define K2EXP 0.12752551286084112f   // (1/sqrt(128)) * log2(e)
#define RTHR 62.0f                   // defer-max threshold in raw-score units
#define NEGS -3.0e38f

typedef __bf16 bf16_t;
typedef __attribute__((ext_vector_type(8))) __bf16 bf16x8;
typedef __attribute__((ext_vector_type(4))) __bf16 bf16x4;
typedef __attribute__((ext_vector_type(4))) float f32x4;
typedef __attribute__((ext_vector_type(16))) float f32x16;

#define MFMA16 __builtin_amdgcn_mfma_f32_16x16x32_bf16
#define MFMA32 __builtin_amdgcn_mfma_f32_32x32x16_bf16

__device__ __forceinline__ unsigned cvtpk(float lo, float hi) {
  unsigned r;
  asm("v_cvt_pk_bf16_f32 %0, %1, %2" : "=v"(r) : "v"(lo), "v"(hi));
  return r;
}
__device__ __forceinline__ void plswap(unsigned& a, unsigned& b) {
  asm volatile("v_permlane32_swap_b32 %0, %1" : "+v"(a), "+v"(b));
}
__device__ __forceinline__ bf16x8 mk8(unsigned d0, unsigned d1, unsigned d2, unsigned d3) {
  union { unsigned u[4]; bf16x8 v; } x;
  x.u[0] = d0; x.u[1] = d1; x.u[2] = d2; x.u[3] = d3;
  return x.v;
}

// Tile layouts (per head h, 32-kv tile t; contiguous 4096 halfwords = 8KB):
//  ktb[(h*64+t)*4096 + row*128 + c*8 + e] = hid[32t+row][h*DH + 8*(c^(row&7)) + e]
//  vtb[(h*64+t)*4096 + d*32   + c*8 + e] = hid[32t + 8*(c^(d&3)) + e][h*DH + d]
// Fragment reads partition each tile across lanes (read-once) -> stage directly to VGPRs.

// ---------------- mask precompute: intervals + starts + landmarks + 32q-stripe meta ----------------
__global__ __launch_bounds__(256) void maskprep2(const int* __restrict__ tokens,
                                                 const unsigned char* __restrict__ seg,
                                                 const unsigned char* __restrict__ spc,
                                                 int4* __restrict__ mi,
                                                 int* __restrict__ lq,
                                                 unsigned long long* __restrict__ lmask,
                                                 int2* __restrict__ smeta) {
  __shared__ int ssp[257], ssg[257], smw[257], sms[257], sfl[257];
  __shared__ int fpre[2048];
  __shared__ int ns64[64];
  __shared__ unsigned long long lmk[32];
  __shared__ int cdet[2];
  int t = threadIdx.x;
  if (t < 2) cdet[t] = 0;
  if (t < 32) lmk[t] = 0ull;
  __syncthreads();
  {
    int nz = ((t & 3) != 0 && seg[t]) ? 1 : 0;
    int fc = ((t & 3) == 3 && seg[t] == 0x3f) ? 1 : 0;
    if (nz) atomicAdd(&cdet[0], 1);
    if (fc) atomicAdd(&cdet[1], 1);
  }
  __syncthreads();
  int lay = (cdet[1] > 8) ? 2 : ((cdet[0] > 4) ? 1 : 0);
  auto getb = [&](const unsigned char* p, int i) -> int {
    if (lay == 1) return p[i] != 0;
    if (lay == 2) return ((const float*)p)[i] != 0.f;
    return ((const int*)p)[i] != 0;
  };
  int base = t * 8;
  int spv[8], sgv[8], npv[8], fv[8];
  int a = 0, b = 0, mw = 0, ms = 0, fs = 0;
  for (int j = 0; j < 8; j++) {
    int i = base + j;
    spv[j] = getb(spc, i);
    sgv[j] = 1 - getb(seg, i);
    npv[j] = (tokens[i] != 127) ? 1 : 0;
    fv[j] = spv[j] & sgv[j] & npv[j];
    a += spv[j]; b += sgv[j]; fs += fv[j];
    if (i >= 1 && spv[j]) mw = (i + 1 > mw) ? i + 1 : mw;
    if (i >= 1 && sgv[j]) ms = (i + 1 > ms) ? i + 1 : ms;
  }
  ssp[t + 1] = a; ssg[t + 1] = b; smw[t + 1] = mw; sms[t + 1] = ms; sfl[t + 1] = fs;
  if (t == 0) { ssp[0] = 0; ssg[0] = 0; smw[0] = 0; sms[0] = 0; sfl[0] = 0; }
  __syncthreads();
  for (int off = 1; off < 256; off <<= 1) {
    int v0 = 0, v1 = 0, v2 = 0, v3 = 0, v4 = 0;
    if (t + 1 > off) { v0 = ssp[t+1-off]; v1 = ssg[t+1-off]; v2 = smw[t+1-off]; v3 = sms[t+1-off]; v4 = sfl[t+1-off]; }
    __syncthreads();
    ssp[t + 1] += v0; ssg[t + 1] += v1;
    if (v2 > smw[t + 1]) smw[t + 1] = v2;
    if (v3 > sms[t + 1]) sms[t + 1] = v3;
    sfl[t + 1] += v4;
    __syncthreads();
  }
  if ((t & 3) == 0) {
    int ws = smw[t], ss = sms[t];
    ns64[t >> 2] = ws < ss ? ws : ss;
  }
  int esp = ssp[t], esg = ssg[t], ef = sfl[t];
  for (int j = 0; j < 8; j++) {
    int i = base + j;
    int wint = (i == 0) ? (1 + spv[j]) : (1 + esp);
    int sint = (i == 0) ? (1 + sgv[j]) : (1 + esg);
    mi[i] = make_int4(npv[j] | (spv[j] << 1) | (sgv[j] << 2), wint, sint, 0);
    fpre[i] = ef;
    int lqv = (fv[j] && ef < LCAP) ? ef : -1;
    lq[i] = lqv;
    if (lqv >= 0) atomicOr(&lmk[i >> 6], 1ull << (i & 63));
    esp += spv[j]; esg += sgv[j]; ef += fv[j];
  }
  __syncthreads();
  if (t < 32) lmask[t] = lmk[t];
  if (t < 64) {
    int nsTile = ns64[t] >> 5;           // 32-kv tile index
    int lc = fpre[nsTile * 32];          // landmarks strictly below near zone
    if (lc > LCAP) lc = LCAP;
    smeta[t] = make_int2(nsTile, lc);
  }
}

// ---------------- megaprep: embed(ktb/vtb/landmarks) + bitgen + wcvt in one launch ----------------
__global__ __launch_bounds__(256) void megaprep(const int* __restrict__ tokens,
                                                const float* __restrict__ emb,
                                                const int4* __restrict__ mi,
                                                const int* __restrict__ lq,
                                                const unsigned long long* __restrict__ lmask,
                                                const float* __restrict__ lm_w,
                                                bf16_t* __restrict__ wbf,
                                                unsigned* __restrict__ cmask,
                                                bf16_t* __restrict__ ktb,
                                                bf16_t* __restrict__ vtb,
                                                bf16_t* __restrict__ ktbL,
                                                bf16_t* __restrict__ vtbL) {
  __shared__ __align__(16) bf16_t tile[64 * 136];
  int bid = blockIdx.x;
  int tid = threadIdx.x;

  if (bid < 512) {
    int qblk = bid & 31, h = bid >> 5;
    int q0 = qblk * 64;
    int ql = tid >> 2, d0 = (tid & 3) * 32;
    int tok = tokens[q0 + ql];
    const float4* src = (const float4*)(emb + (size_t)tok * HID + h * DH + d0);
    #pragma unroll
    for (int i = 0; i < 8; i++) {
      float4 f = src[i];
      tile[ql * 136 + d0 + i * 4 + 0] = (bf16_t)f.x;
      tile[ql * 136 + d0 + i * 4 + 1] = (bf16_t)f.y;
      tile[ql * 136 + d0 + i * 4 + 2] = (bf16_t)f.z;
      tile[ql * 136 + d0 + i * 4 + 3] = (bf16_t)f.w;
    }
    __syncthreads();
    {
      int tl2 = tid >> 7, half = (tid >> 6) & 1, lane = tid & 63;
      bf16_t* kt = ktb + ((size_t)(h * 64) + 2 * qblk + tl2) * 4096;
      #pragma unroll
      for (int k = 0; k < 4; k++) {
        int s = half * 4 + k;
        int row = s * 4 + (lane >> 4);
        int c = lane & 15;
        bf16x8 v;
        #pragma unroll
        for (int e = 0; e < 8; e++)
          v[e] = tile[(32 * tl2 + row) * 136 + 8 * (c ^ (row & 7)) + e];
        *(bf16x8*)(kt + s * 512 + lane * 8) = v;
      }
    }
    {
      int tl2 = tid >> 7, d = tid & 127;
      bf16_t* vt = vtb + ((size_t)(h * 64) + 2 * qblk + tl2) * 4096;
      #pragma unroll
      for (int c = 0; c < 4; c++) {
        bf16x8 v;
        #pragma unroll
        for (int e = 0; e < 8; e++)
          v[e] = tile[(32 * tl2 + 8 * (c ^ (d & 3)) + e) * 136 + d];
        *(bf16x8*)(vt + d * 32 + c * 8) = v;
      }
    }
    unsigned long long lm = lmask[q0 >> 6];
    while (lm) {
      int r = __builtin_ctzll(lm);
      lm &= lm - 1;
      int li = lq[q0 + r];
      if (li >= 0 && tid < 128) {
        int dd = tid;
        bf16_t vv = tile[r * 136 + dd];
        int row = li & 31, jt = li >> 5;
        ktbL[((size_t)(h * 4) + jt) * 4096 + row * 128 + ((dd >> 3) ^ (row & 7)) * 8 + (dd & 7)] = vv;
        vtbL[((size_t)(h * 4) + jt) * 4096 + dd * 32 + ((row >> 3) ^ (dd & 3)) * 8 + (row & 7)] = vv;
      }
    }
  } else if (bid < 1024) {
    __shared__ int4 km[32];
    int b2 = bid - 512;
    int w = b2 & 63, y = b2 >> 6;
    int q = y * 256 + tid;
    if (tid < 32) km[tid] = mi[w * 32 + tid];
    __syncthreads();
    int4 mq = mi[q];
    unsigned word = 0;
    #pragma unroll
    for (int j = 0; j < 32; j++) {
      int kv = w * 32 + j;
      int4 mk = km[j];
      bool v = ((mq.x & mk.x) & 1) &&
               ((mk.x & 2) || (mq.y == mk.y)) &&
               ((mk.x & 4) || (mq.z == mk.z)) &&
               (kv <= q);
      word |= (v ? 1u : 0u) << j;
    }
    cmask[(size_t)w * S + q] = word;
  } else {
    int i = (bid - 1024) * 256 + tid;
    float4 f = ((const float4*)lm_w)[i];
    bf16x4 v;
    v[0] = (bf16_t)f.x; v[1] = (bf16_t)f.y; v[2] = (bf16_t)f.z; v[3] = (bf16_t)f.w;
    *(bf16x4*)(wbf + (size_t)i * 4) = v;
  }
}

// ---------------- fused attention layer: 1 wave / 32-q stripe, register-staged K+V ----------------
__global__ __launch_bounds__(64) void attn10(const bf16_t* __restrict__ ktb,
                                             const bf16_t* __restrict__ vtb,
                                             const bf16_t* __restrict__ ktbL,
                                             const bf16_t* __restrict__ vtbL,
                                             const unsigned* __restrict__ cmask,
                                             const int4* __restrict__ mi,
                                             const int2* __restrict__ smeta,
                                             const int* __restrict__ lq,
                                             const unsigned long long* __restrict__ lmask,
                                             bf16_t* __restrict__ oktb,
                                             bf16_t* __restrict__ ovtb,
                                             bf16_t* __restrict__ oktbL,
                                             bf16_t* __restrict__ ovtbL,
                                             bf16_t* __restrict__ hbF,
                                             int writeT) {
  __shared__ __align__(16) bf16_t tl[32 * 132];   // epilogue transpose tile only

  int h = blockIdx.x, st = blockIdx.y;            // st 0..63, 32 q each
  int2 sm = smeta[st];
  int nsT = sm.x, lcount = sm.y;
  int nNear = st + 1 - nsT;
  int nLT = (lcount + 31) >> 5;
  int nIter = nNear + nLT;

  int l = threadIdx.x, l31 = l & 31, hi = l >> 5;
  int q0 = 32 * st, q = q0 + l31;
  int npq = mi[q].x & 1;
  int swz = l31 & 7;

  // Q fragments from my own ktb tile (h, st)
  bf16x8 qf[8];
  {
    const bf16_t* kt0 = ktb + ((size_t)(h * 64) + st) * 4096;
    #pragma unroll
    for (int ks = 0; ks < 8; ks++)
      qf[ks] = *(const bf16x8*)(kt0 + l31 * 128 + (((2 * ks + hi) ^ swz) * 8));
  }

  f32x16 acc[4];
  #pragma unroll
  for (int i = 0; i < 4; i++)
    #pragma unroll
    for (int r = 0; r < 16; r++) acc[i][r] = 0.f;
  float m = -1e30f, lsum = 0.f;

  auto LOADT = [&](int i, bf16x8* kf, bf16x8* vf) {
    const bf16_t* Ktile; const bf16_t* Vtile;
    if (i < nNear) {
      int t = nsT + i;
      Ktile = ktb + ((size_t)(h * 64) + t) * 4096;
      Vtile = vtb + ((size_t)(h * 64) + t) * 4096;
    } else {
      int j = i - nNear;
      Ktile = ktbL + ((size_t)(h * 4) + j) * 4096;
      Vtile = vtbL + ((size_t)(h * 4) + j) * 4096;
    }
    const bf16_t* kp = Ktile + l31 * 128;
    #pragma unroll
    for (int ks = 0; ks < 8; ks++)
      kf[ks] = *(const bf16x8*)(kp + (((2 * ks + hi) ^ swz) * 8));
    #pragma unroll
    for (int j2 = 0; j2 < 8; j2++) {
      int db = j2 >> 1, ks = j2 & 1;
      vf[j2] = *(const bf16x8*)(Vtile + (size_t)(32 * db + l31) * 32 + (((2 * ks + hi) ^ (l31 & 3)) * 8));
    }
  };

  auto COMPUTE = [&](int i, const bf16x8* kf, const bf16x8* vf) {
    unsigned w0;
    if (i < nNear) {
      w0 = cmask[(size_t)(nsT + i) * S + q];
    } else {
      int rem = lcount - (i - nNear) * 32;
      w0 = (rem >= 32) ? 0xffffffffu : ((rem <= 0) ? 0u : ((1u << rem) - 1u));
      w0 = npq ? w0 : 0u;
    }
    if (!__any(w0 != 0u)) return;

    f32x16 sA, sB;
    #pragma unroll
    for (int r = 0; r < 16; r++) { sA[r] = 0.f; sB[r] = 0.f; }
    #pragma unroll
    for (int ks = 0; ks < 8; ks += 2) {
      sA = MFMA32(kf[ks], qf[ks], sA, 0, 0, 0);
      sB = MFMA32(kf[ks + 1], qf[ks + 1], sB, 0, 0, 0);
    }

    float sv[16];
    #pragma unroll
    for (int r = 0; r < 16; r++) {
      int bit = (r & 3) + 8 * (r >> 2) + 4 * hi;
      float sr = sA[r] + sB[r];
      sv[r] = ((w0 >> bit) & 1u) ? sr : NEGS;
    }
    float t0 = fmaxf(fmaxf(sv[0], sv[1]), fmaxf(sv[2], sv[3]));
    float t1 = fmaxf(fmaxf(sv[4], sv[5]), fmaxf(sv[6], sv[7]));
    float t2 = fmaxf(fmaxf(sv[8], sv[9]), fmaxf(sv[10], sv[11]));
    float t3 = fmaxf(fmaxf(sv[12], sv[13]), fmaxf(sv[14], sv[15]));
    float mx = fmaxf(fmaxf(t0, t1), fmaxf(t2, t3));
    mx = fmaxf(mx, __shfl_xor(mx, 32, 64));
    if (__any(mx > m + RTHR)) {
      float mn = fmaxf(m, mx);
      float al = exp2f((m - mn) * K2EXP);
      m = mn; lsum *= al;
      #pragma unroll
      for (int r = 0; r < 16; r++) {
        float alr = __shfl(al, (r & 3) + 8 * (r >> 2) + 4 * hi, 64);
        #pragma unroll
        for (int d = 0; d < 4; d++) acc[d][r] *= alr;
      }
    }
    float mk = m * K2EXP;
    float p[16];
    #pragma unroll
    for (int r = 0; r < 16; r++)
      p[r] = exp2f(__builtin_fmaf(sv[r], K2EXP, -mk));
    float u0 = (p[0] + p[1]) + (p[2] + p[3]);
    float u1 = (p[4] + p[5]) + (p[6] + p[7]);
    float u2 = (p[8] + p[9]) + (p[10] + p[11]);
    float u3 = (p[12] + p[13]) + (p[14] + p[15]);
    float ps = (u0 + u1) + (u2 + u3);
    ps += __shfl_xor(ps, 32, 64);
    lsum += ps;

    bf16x8 pa[2];
    {
      unsigned a0 = cvtpk(p[0], p[1]),   a1 = cvtpk(p[2], p[3]);
      unsigned b0 = cvtpk(p[4], p[5]),   b1 = cvtpk(p[6], p[7]);
      unsigned a2 = cvtpk(p[8], p[9]),   a3 = cvtpk(p[10], p[11]);
      unsigned b2 = cvtpk(p[12], p[13]), b3 = cvtpk(p[14], p[15]);
      plswap(a0, b0); plswap(a1, b1); plswap(a2, b2); plswap(a3, b3);
      pa[0] = mk8(a0, a1, b0, b1);
      pa[1] = mk8(a2, a3, b2, b3);
    }

    #pragma unroll
    for (int db = 0; db < 4; db++) {
      #pragma unroll
      for (int ks = 0; ks < 2; ks++)
        acc[db] = MFMA32(pa[ks], vf[db * 2 + ks], acc[db], 0, 0, 0);
    }
  };

  bf16x8 kfA[8], vfA[8], kfB[8], vfB[8];
  LOADT(0, kfA, vfA);
  for (int i = 0; i < nIter; i += 2) {
    if (i + 1 < nIter) LOADT(i + 1, kfB, vfB);
    COMPUTE(i, kfA, vfA);
    if (i + 2 < nIter) LOADT(i + 2, kfA, vfA);
    if (i + 1 < nIter) COMPUTE(i + 1, kfB, vfB);
  }

  // epilogue (single wave, DS ops wave-ordered: no barriers)
  float inv = (lsum > 0.f) ? 1.f / lsum : 0.f;
  #pragma unroll
  for (int r = 0; r < 16; r++) {
    int qr = (r & 3) + 8 * (r >> 2) + 4 * hi;
    float ivr = __shfl(inv, qr, 64);
    #pragma unroll
    for (int db = 0; db < 4; db++)
      tl[qr * 132 + db * 32 + l31] = (bf16_t)(acc[db][r] * ivr);
  }
  if (writeT) {
    bf16_t* kt = oktb + ((size_t)(h * 64) + st) * 4096;
    #pragma unroll
    for (int s = 0; s < 8; s++) {
      int row = s * 4 + (l >> 4);
      int c = l & 15;
      bf16x8 v;
      #pragma unroll
      for (int e = 0; e < 8; e++)
        v[e] = tl[row * 132 + 8 * (c ^ (row & 7)) + e];
      *(bf16x8*)(kt + s * 512 + l * 8) = v;
    }
    bf16_t* vt = ovtb + ((size_t)(h * 64) + st) * 4096;
    #pragma unroll
    for (int s = 0; s < 8; s++) {
      int d = s * 16 + (l >> 2);
      bf16x8 v;
      #pragma unroll
      for (int e = 0; e < 8; e++)
        v[e] = tl[(8 * ((l & 3) ^ (d & 3)) + e) * 132 + d];
      *(bf16x8*)(vt + s * 512 + l * 8) = v;
    }
    unsigned lm32 = (unsigned)(lmask[st >> 1] >> ((st & 1) * 32));
    while (lm32) {
      int r = __builtin_ctz(lm32);
      lm32 &= lm32 - 1;
      int li = lq[q0 + r];
      if (li >= 0) {
        int row = li & 31, jt = li >> 5;
        #pragma unroll
        for (int half = 0; half < 2; half++) {
          int dd = l + 64 * half;
          bf16_t vv = tl[r * 132 + dd];
          oktbL[((size_t)(h * 4) + jt) * 4096 + row * 128 + ((dd >> 3) ^ (row & 7)) * 8 + (dd & 7)] = vv;
          ovtbL[((size_t)(h * 4) + jt) * 4096 + dd * 32 + ((row >> 3) ^ (dd & 3)) * 8 + (row & 7)] = vv;
        }
      }
    }
  } else {
    int c4 = l & 3;
    #pragma unroll
    for (int g = 0; g < 2; g++) {
      int row = g * 16 + (l >> 2);
      #pragma unroll
      for (int k = 0; k < 4; k++) {
        bf16x8 v = *(const bf16x8*)(tl + row * 132 + c4 * 32 + k * 8);
        *(bf16x8*)(hbF + (size_t)(q0 + row) * HID + h * DH + c4 * 32 + k * 8) = v;
      }
    }
  }
}

// ---------------- lm head + segment head fused ----------------
__global__ __launch_bounds__(256) void lmseg_head(const bf16_t* __restrict__ hb,
                                                  const bf16_t* __restrict__ wbf,
                                                  const float* __restrict__ bias,
                                                  const float* __restrict__ sw,
                                                  const float* __restrict__ sb,
                                                  float* __restrict__ out,
                                                  float* __restrict__ outseg) {
  __shared__ float red[4][16][130];
  int tid = threadIdx.x;
  int w = tid >> 6, l = tid & 63, l16 = l & 15, g = l >> 4;
  int t0 = blockIdx.x * 16;
  f32x4 acc[8];
  #pragma unroll
  for (int i = 0; i < 8; i++) acc[i] = (f32x4){0.f, 0.f, 0.f, 0.f};
  const bf16_t* arow = hb + (size_t)(t0 + l16) * HID + w * 512;
  for (int k0 = 0; k0 < 512; k0 += 32) {
    bf16x8 af = *(const bf16x8*)(arow + k0 + g * 8);
    #pragma unroll
    for (int vt = 0; vt < 8; vt++) {
      bf16x8 bf_ = *(const bf16x8*)(wbf + (size_t)(vt * 16 + l16) * HID + w * 512 + k0 + g * 8);
      acc[vt] = MFMA16(af, bf_, acc[vt], 0, 0, 0);
    }
  }
  #pragma unroll
  for (int vt = 0; vt < 8; vt++)
    #pragma unroll
    for (int r = 0; r < 4; r++)
      red[w][4 * g + r][vt * 16 + l16] = acc[vt][r];
  __syncthreads();
  int q = tid >> 4, vc = (tid & 15) * 8;
  #pragma unroll
  for (int j = 0; j < 8; j++) {
    float s = red[0][q][vc + j] + red[1][q][vc + j] + red[2][q][vc + j] + red[3][q][vc + j];
    out[(size_t)(t0 + q) * VOC + vc + j] = s + bias[vc + j];
  }
  {
    int c = tid & 15;
    const bf16_t* hrow = hb + (size_t)(t0 + q) * HID + c * 128;
    float s0 = 0.f, s1 = 0.f;
    #pragma unroll
    for (int i = 0; i < 16; i++) {
      bf16x8 v = *(const bf16x8*)(hrow + i * 8);
      const float4* w0p = (const float4*)(sw + c * 128 + i * 8);
      const float4* w1p = (const float4*)(sw + HID + c * 128 + i * 8);
      float4 x0 = w0p[0], x1 = w0p[1], y0 = w1p[0], y1 = w1p[1];
      s0 += (float)v[0]*x0.x + (float)v[1]*x0.y + (float)v[2]*x0.z + (float)v[3]*x0.w
          + (float)v[4]*x1.x + (float)v[5]*x1.y + (float)v[6]*x1.z + (float)v[7]*x1.w;
      s1 += (float)v[0]*y0.x + (float)v[1]*y0.y + (float)v[2]*y0.z + (float)v[3]*y0.w
          + (float)v[4]*y1.x + (float)v[5]*y1.y + (float)v[6]*y1.z + (float)v[7]*y1.w;
    }
    #pragma unroll
    for (int off = 1; off < 16; off <<= 1) {
      s0 += __shfl_xor(s0, off, 64);
      s1 += __shfl_xor(s1, off, 64);
    }
    if (c == 0) {
      outseg[(size_t)(t0 + q) * 2] = s0 + sb[0];
      outseg[(size_t)(t0 + q) * 2 + 1] = s1 + sb[1];
    }
  }
}

extern "C" void kernel_launch(void* const* d_in, const int* in_sizes, int n_in,
                              void* d_out, int out_size, void* d_ws, size_t ws_size,
                              hipStream_t stream) {
  const int* tokens = (const int*)d_in[0];
  const unsigned char* seg = (const unsigned char*)d_in[1];
  const unsigned char* spc = (const unsigned char*)d_in[2];
  const float* emb_w = (const float*)d_in[3];
  const float* lm_w = (const float*)d_in[4];
  const float* lm_b = (const float*)d_in[5];
  const float* seg_w = (const float*)d_in[6];
  const float* seg_b = (const float*)d_in[7];

  char* ws = (char*)d_ws;
  int4* mi = (int4*)ws;                                              // 32KB @0
  unsigned* cmask = (unsigned*)(ws + (1u << 20));                    // 512KB @1MB
  int* lq = (int*)(ws + (1u << 20) + (512u << 10));                  // 8KB
  unsigned long long* lmask = (unsigned long long*)(ws + (1u << 20) + (520u << 10)); // 256B
  int2* smeta = (int2*)(ws + (1u << 20) + (524u << 10));             // 512B
  bf16_t* wbf = (bf16_t*)(ws + (2u << 20));                          // 512KB @2MB
  bf16_t* ktbLA = (bf16_t*)(ws + (3u << 20));                        // 512KB @3MB
  bf16_t* ktbLB = (bf16_t*)(ws + (3u << 20) + (512u << 10));         // 512KB
  bf16_t* vtbLA = (bf16_t*)(ws + (4u << 20));                        // 512KB @4MB
  bf16_t* vtbLB = (bf16_t*)(ws + (4u << 20) + (512u << 10));         // 512KB
  bf16_t* hbF  = (bf16_t*)(ws + (8u << 20));                         // 8MB @8MB
  bf16_t* ktbA = (bf16_t*)(ws + (16u << 20));                        // 8MB @16MB
  bf16_t* ktbB = (bf16_t*)(ws + (24u << 20));                        // 8MB @24MB
  bf16_t* vtbA = (bf16_t*)(ws + (32u << 20));                        // 8MB @32MB
  bf16_t* vtbB = (bf16_t*)(ws + (40u << 20));                        // 8MB @40MB
  float* out = (float*)d_out;

  maskprep2<<<1, 256, 0, stream>>>(tokens, seg, spc, mi, lq, lmask, smeta);
  megaprep<<<1280, 256, 0, stream>>>(tokens, emb_w, mi, lq, lmask, lm_w, wbf, cmask,
                                     ktbA, vtbA, ktbLA, vtbLA);

  bf16_t* curK = ktbA;  bf16_t* curV = vtbA;
  bf16_t* nxtK = ktbB;  bf16_t* nxtV = vtbB;
  bf16_t* curKL = ktbLA; bf16_t* curVL = vtbLA;
  bf16_t* nxtKL = ktbLB; bf16_t* nxtVL = vtbLB;
  for (int L = 0; L < 4; L++) {
    attn10<<<dim3(NH, 64), 64, 0, stream>>>(curK, curV, curKL, curVL, cmask, mi, smeta, lq, lmask,
                                            nxtK, nxtV, nxtKL, nxtVL, hbF, (L < 3) ? 1 : 0);
    bf16_t* t1 = curK; curK = nxtK; nxtK = t1;
    bf16_t* t2 = curV; curV = nxtV; nxtV = t2;
    bf16_t* t3 = curKL; curKL = nxtKL; nxtKL = t3;
    bf16_t* t4 = curVL; curVL = nxtVL; nxtVL = t4;
  }

  lmseg_head<<<S / 16, 256, 0, stream>>>(hbF, wbf, lm_b, seg_w, seg_b, out, out + (size_t)S * VOC);
}